// Round 3
// baseline (840.562 us; speedup 1.0000x reference)
//
#include <hip/hip_runtime.h>
#include <hip/hip_bf16.h>

// Problem constants (fixed by the reference).
#define BB   128
#define NN   500
#define NV   64000        // BB*NN nodes
#define EE   1048576      // edges
#define DD   128
#define FIN  5
#define VNN  10

typedef unsigned int   uint32;
typedef unsigned short u16b;

// fp32 param-block layout (element offsets)
#define P_WF    0          // 4*128*128
#define P_ASRC  65536      // 4*128
#define P_ADST  66048      // 4*128
#define P_WE    66560      // 4*2*128
#define P_BIAS  67584      // 4*128
#define P_W5    68096      // 128
#define P_CVEC  68224      // 12
#define P_SC5   68236      // b5, as5, ad5
#define P_TOT   68352

static __device__ __forceinline__ float bf2f(__hip_bfloat16 v) { return __bfloat162float(v); }
static __device__ __forceinline__ float lo2f(uint32 u) { return __uint_as_float(u << 16); }
static __device__ __forceinline__ float hi2f(uint32 u) { return __uint_as_float(u & 0xFFFF0000u); }
static __device__ __forceinline__ uint32 f2bf_bits(float f) {
    uint32 u = __float_as_uint(f);
    return (u + 0x7FFFu + ((u >> 16) & 1u)) >> 16;
}
static __device__ __forceinline__ uint32 pack2(float a, float b) {
    return (f2bf_bits(a) & 0xFFFFu) | (f2bf_bits(b) << 16);
}
// flag-dispatched loads: flag==1 -> fp32 container, flag==0 -> bf16 container
static __device__ __forceinline__ float ldf(const void* p, int i, int flag) {
    return flag ? ((const float*)p)[i] : bf2f(((const __hip_bfloat16*)p)[i]);
}
static __device__ __forceinline__ float2 lde2(const void* p, int e, int flag) {
    if (flag) return ((const float2*)p)[e];
    uint32 u = ((const uint32*)p)[e];
    return make_float2(lo2f(u), hi2f(u));
}

// ---------------------------------------------------------------------------
// dtype sniffer on edge_attr (uniform[0,1)):
//  bf16 container: every 16-bit half in [0, 0x3F80)  -> flag 0
//  fp32 container: even halves random (>=0x8000 half the time) or all zero
__global__ void sniff_kernel(const unsigned short* __restrict__ p16, int* __restrict__ FLAG) {
    __shared__ int sHigh, sZero;
    if (threadIdx.x == 0) { sHigh = 0; sZero = 0; }
    __syncthreads();
    unsigned short v = p16[2 * threadIdx.x];
    if (v >= 0x8000u) atomicOr(&sHigh, 1);
    if (v == 0)       atomicAdd(&sZero, 1);
    __syncthreads();
    if (threadIdx.x == 0) FLAG[0] = (sHigh || sZero >= 128) ? 1 : 0;
}

// fallback when workspace is too small: zeros + ws_size tag in out[0]
__global__ void zero_out_kernel(void* __restrict__ out, const int* __restrict__ FLAG, float tag) {
    int i = blockIdx.x * blockDim.x + threadIdx.x;
    if (i >= NV) return;
    float v = (i == 0) ? tag : 0.f;
    if (FLAG[0]) ((float*)out)[i] = v;
    else         ((u16b*)out)[i] = (u16b)f2bf_bits(v);
}

// ---------------------------------------------------------------------------
// prep: canonicalize all weights to fp32 PAR block; attention-edge scalars.
__global__ void prep_kernel(const void* __restrict__ Ws, const void* __restrict__ Wes,
                            const void* __restrict__ aeg, const void* __restrict__ We5,
                            const void* __restrict__ ae5, const void* __restrict__ asr,
                            const void* __restrict__ ads, const void* __restrict__ bs,
                            const void* __restrict__ W5, const void* __restrict__ b5,
                            const void* __restrict__ as5, const void* __restrict__ ad5,
                            const int* __restrict__ FLAG, float* __restrict__ PAR) {
    const int flag = FLAG[0];
    int t = blockIdx.x * blockDim.x + threadIdx.x;
    for (int i = t; i < 4 * DD * DD; i += gridDim.x * blockDim.x)
        PAR[P_WF + i] = ldf(Ws, i, flag);
    if (blockIdx.x == 0) {
        for (int i = threadIdx.x; i < 512; i += 256) PAR[P_ASRC + i] = ldf(asr, i, flag);
    } else if (blockIdx.x == 1) {
        for (int i = threadIdx.x; i < 512; i += 256) PAR[P_ADST + i] = ldf(ads, i, flag);
    } else if (blockIdx.x == 2) {
        for (int i = threadIdx.x; i < 1024; i += 256) PAR[P_WE + i] = ldf(Wes, i, flag);
    } else if (blockIdx.x == 3) {
        for (int i = threadIdx.x; i < 512; i += 256) PAR[P_BIAS + i] = ldf(bs, i, flag);
    } else if (blockIdx.x == 4) {
        int tid = threadIdx.x;
        if (tid < 128) {
            PAR[P_W5 + tid] = ldf(W5, tid, flag);
        } else if (tid < 136) {
            int l = (tid - 128) >> 1, r = (tid - 128) & 1;
            float s = 0.f;
            for (int ch = 0; ch < DD; ++ch)
                s += ldf(Wes, l * 256 + r * DD + ch, flag) * ldf(aeg, l * DD + ch, flag);
            PAR[P_CVEC + l * 2 + r] = s;
        } else if (tid == 136) {
            float ae = ldf(ae5, 0, flag);
            float w0 = ldf(We5, 0, flag), w1 = ldf(We5, 1, flag);
            PAR[P_CVEC + 8] = w0 * ae; PAR[P_CVEC + 9] = w1 * ae;
            PAR[P_CVEC + 10] = w0;     PAR[P_CVEC + 11] = w1;
            PAR[P_SC5 + 0] = ldf(b5, 0, flag);
            PAR[P_SC5 + 1] = ldf(as5, 0, flag);
            PAR[P_SC5 + 2] = ldf(ad5, 0, flag);
        }
    }
}

// ---------------------------------------------------------------------------
// input projection: h0 = lrelu(x@pW + pb, .01) + vge[b] + vnd[b, curr[b]]
__global__ __launch_bounds__(64) void proj_kernel(
        const void* __restrict__ x, const void* __restrict__ pW,
        const void* __restrict__ pb, const int* __restrict__ curr,
        const void* __restrict__ vge, const void* __restrict__ vnd,
        const int* __restrict__ FLAG, uint32* __restrict__ H) {
    const int flag = FLAG[0];
    const int n = blockIdx.x, lane = threadIdx.x;
    const int b = n / NN;
    int cv = curr[b]; if ((unsigned)cv >= VNN) cv = 0;
    float xv[FIN];
#pragma unroll
    for (int k = 0; k < FIN; ++k) xv[k] = ldf(x, n * FIN + k, flag);
    const int ch = lane * 2;
    float s0 = ldf(pb, ch, flag), s1 = ldf(pb, ch + 1, flag);
#pragma unroll
    for (int k = 0; k < FIN; ++k) {
        s0 = fmaf(xv[k], ldf(pW, k * DD + ch, flag), s0);
        s1 = fmaf(xv[k], ldf(pW, k * DD + ch + 1, flag), s1);
    }
    s0 = (s0 > 0.f) ? s0 : 0.01f * s0;
    s1 = (s1 > 0.f) ? s1 : 0.01f * s1;
    s0 += ldf(vge, b * DD + ch, flag) + ldf(vnd, (b * VNN + cv) * DD + ch, flag);
    s1 += ldf(vge, b * DD + ch + 1, flag) + ldf(vnd, (b * VNN + cv) * DD + ch + 1, flag);
    H[n * 64 + lane] = pack2(s0, s1);
}

// ---------------------------------------------------------------------------
// CSR build: histogram -> scan -> scatter (counting sort by dst)
__global__ void hist_kernel(const int* __restrict__ dst, int* __restrict__ counts) {
    for (int e = blockIdx.x * blockDim.x + threadIdx.x; e < EE; e += gridDim.x * blockDim.x) {
        int d = dst[e];
        if ((unsigned)d < NV) atomicAdd(&counts[d], 1);
    }
}

__global__ __launch_bounds__(256) void scan1_kernel(const int* __restrict__ counts,
                                                    int* __restrict__ row_ptr,
                                                    int* __restrict__ partials) {
    __shared__ int sdata[256];
    int tid = threadIdx.x;
    int4 v = ((const int4*)counts)[blockIdx.x * 256 + tid];
    int sum = v.x + v.y + v.z + v.w;
    sdata[tid] = sum;
    __syncthreads();
    int acc = sum;
    for (int off = 1; off < 256; off <<= 1) {
        int t = (tid >= off) ? sdata[tid - off] : 0;
        __syncthreads();
        acc += t;
        sdata[tid] = acc;
        __syncthreads();
    }
    int excl = acc - sum;
    int base = blockIdx.x * 1024 + tid * 4;
    int run = excl;
    if (base + 0 <= NV) row_ptr[base + 0] = run; run += v.x;
    if (base + 1 <= NV) row_ptr[base + 1] = run; run += v.y;
    if (base + 2 <= NV) row_ptr[base + 2] = run; run += v.z;
    if (base + 3 <= NV) row_ptr[base + 3] = run;
    if (tid == 255) partials[blockIdx.x] = acc;
}

__global__ __launch_bounds__(64) void scan2_kernel(const int* __restrict__ partials,
                                                   int* __restrict__ boff, int nb) {
    int lane = threadIdx.x;
    int v = (lane < nb) ? partials[lane] : 0;
    int orig = v;
#pragma unroll
    for (int off = 1; off < 64; off <<= 1) {
        int t = __shfl_up(v, off, 64);
        if (lane >= off) v += t;
    }
    boff[lane] = v - orig;
}

__global__ __launch_bounds__(256) void scan3_kernel(int* __restrict__ row_ptr,
                                                    const int* __restrict__ boff,
                                                    int* __restrict__ cursor) {
    int add = boff[blockIdx.x];
    int base = blockIdx.x * 1024 + threadIdx.x * 4;
#pragma unroll
    for (int j = 0; j < 4; ++j) {
        int i = base + j;
        if (i <= NV) {
            int r = row_ptr[i] + add;
            row_ptr[i] = r;
            if (i < NV) cursor[i] = r;
        }
    }
}

// CSR entry: {src, edge_id}
__global__ void scatter_kernel(const int* __restrict__ src, const int* __restrict__ dst,
                               int* __restrict__ cursor, int2* __restrict__ csr) {
    for (int e = blockIdx.x * blockDim.x + threadIdx.x; e < EE; e += gridDim.x * blockDim.x) {
        int d = dst[e];
        if ((unsigned)d >= NV) continue;
        int p = atomicAdd(&cursor[d], 1);
        if ((unsigned)p >= EE) continue;
        csr[p] = make_int2(src[e], e);
    }
}

// ---------------------------------------------------------------------------
// GEMM: HW = H @ W. H bf16-packed, W fp32 (PAR), acc fp32, HW bf16-packed.
// Block = 64 nodes x 64 cols (gridDim.y=2), 4 waves x 16 cols.
__global__ __launch_bounds__(256) void gemm_kernel(
        const uint32* __restrict__ Hu, const float* __restrict__ Wf,
        const float* __restrict__ Asr, const float* __restrict__ Ads,
        uint32* __restrict__ HWu, float* __restrict__ ssrc, float* __restrict__ sdst) {
    __shared__ float hs[64 * 129];
    const int tid = threadIdx.x;
    const int lane = tid & 63;
    const int wave = tid >> 6;
    const int n0 = blockIdx.x * 64;
    const int chB = blockIdx.y * 64;
    const int ch0u = __builtin_amdgcn_readfirstlane(chB + wave * 16);

    {   // stage H tile (bf16 -> fp32)
        const int n = tid & 63;
        const int k0h = (tid >> 6) * 16;     // uint (pair) offset: 16 uints = 32 ch
        const uint4* srcp = (const uint4*)(Hu + (size_t)(n0 + n) * 64 + k0h);
        float* dp = hs + n * 129 + k0h * 2;
#pragma unroll
        for (int i = 0; i < 4; ++i) {
            uint4 v = srcp[i];
            dp[8 * i + 0] = lo2f(v.x); dp[8 * i + 1] = hi2f(v.x);
            dp[8 * i + 2] = lo2f(v.y); dp[8 * i + 3] = hi2f(v.y);
            dp[8 * i + 4] = lo2f(v.z); dp[8 * i + 5] = hi2f(v.z);
            dp[8 * i + 6] = lo2f(v.w); dp[8 * i + 7] = hi2f(v.w);
        }
    }
    __syncthreads();

    float acc[16];
#pragma unroll
    for (int j = 0; j < 16; ++j) acc[j] = 0.f;

    const float* hrow = hs + lane * 129;
#pragma unroll 4
    for (int k = 0; k < DD; ++k) {
        float hk = hrow[k];
        const float* wk = Wf + k * DD + ch0u;   // wave-uniform -> s_load
#pragma unroll
        for (int j = 0; j < 16; ++j) acc[j] = fmaf(hk, wk[j], acc[j]);
    }

    float psrc = 0.f, pdst = 0.f;
#pragma unroll
    for (int j = 0; j < 16; ++j) {
        psrc = fmaf(acc[j], Asr[ch0u + j], psrc);
        pdst = fmaf(acc[j], Ads[ch0u + j], pdst);
    }
    atomicAdd(&ssrc[n0 + lane], psrc);
    atomicAdd(&sdst[n0 + lane], pdst);

    __syncthreads();
#pragma unroll
    for (int j = 0; j < 16; ++j)
        hs[lane * 65 + wave * 16 + j] = acc[j];
    __syncthreads();
#pragma unroll
    for (int i = 0; i < 2; ++i) {
        int flat = i * 2048 + tid * 8;
        int n = flat >> 6, c = flat & 63;
        const float* p = hs + n * 65 + c;
        uint4 v;
        v.x = pack2(p[0], p[1]); v.y = pack2(p[2], p[3]);
        v.z = pack2(p[4], p[5]); v.w = pack2(p[6], p[7]);
        *(uint4*)(HWu + (size_t)(n0 + n) * 64 + (chB + c) / 2) = v;
    }
}

// ---------------------------------------------------------------------------
// Hidden-layer attention + aggregation. One wave per dst node.
__global__ __launch_bounds__(256) void agg_kernel(
        const uint32* __restrict__ HWu, const float* __restrict__ ssrc,
        const float* __restrict__ sdst, const int2* __restrict__ csr,
        const void* __restrict__ eaP, const int* __restrict__ FLAG,
        const int* __restrict__ row_ptr, const float* __restrict__ PAR,
        int layer, uint32* __restrict__ HoutU) {
    const int flag = FLAG[0];
    const int lane = threadIdx.x & 63;
    const int n = blockIdx.x * 4 + (threadIdx.x >> 6);
    int begin = __builtin_amdgcn_readfirstlane(row_ptr[n]);
    int end   = __builtin_amdgcn_readfirstlane(row_ptr[n + 1]);
    if ((unsigned)begin > EE) begin = 0;
    if ((unsigned)end > EE) end = begin;
    int deg = end - begin; if (deg < 0) deg = 0;
    const float c0 = PAR[P_CVEC + 2 * layer], c1 = PAR[P_CVEC + 2 * layer + 1];
    const float sd = sdst[n];

    float m = -3.4e38f;
    for (int j0 = 0; j0 < deg; j0 += 64) {
        int j = j0 + lane;
        if (j < deg) {
            int2 ce = csr[begin + j];
            int s = ((unsigned)ce.x < NV) ? ce.x : 0;
            int ei = ((unsigned)ce.y < EE) ? ce.y : 0;
            float2 ea = lde2(eaP, ei, flag);
            float L = fmaf(ea.y, c1, fmaf(ea.x, c0, ssrc[s] + sd));
            L = (L > 0.f) ? L : 0.2f * L;
            m = fmaxf(m, L);
        }
    }
#pragma unroll
    for (int o = 32; o; o >>= 1) m = fmaxf(m, __shfl_xor(m, o, 64));

    const int ch = lane * 2;
    const float* WEl = PAR + P_WE + layer * 256;
    const float w0x = WEl[ch],      w0y = WEl[ch + 1];
    const float w1x = WEl[DD + ch], w1y = WEl[DD + ch + 1];

    float dsum = 0.f, acc0 = 0.f, acc1 = 0.f;
    for (int jj = 0; jj < deg; ++jj) {
        int2 ce = csr[begin + jj];              // wave-uniform
        int s = ((unsigned)ce.x < NV) ? ce.x : 0;
        int ei = ((unsigned)ce.y < EE) ? ce.y : 0;
        float2 ea = lde2(eaP, ei, flag);
        float L = fmaf(ea.y, c1, fmaf(ea.x, c0, ssrc[s] + sd));
        L = (L > 0.f) ? L : 0.2f * L;
        float ex = __expf(L - m);
        dsum += ex;
        uint32 hb = HWu[(size_t)s * 64 + lane];     // coalesced row gather
        acc0 = fmaf(ex, lo2f(hb) + fmaf(ea.y, w1x, ea.x * w0x), acc0);
        acc1 = fmaf(ex, hi2f(hb) + fmaf(ea.y, w1y, ea.x * w0y), acc1);
    }
    const float inv = 1.f / (dsum + 1e-16f);
    const float* Bl = PAR + P_BIAS + layer * DD;
    float o0 = fmaf(acc0, inv, Bl[ch]);
    float o1 = fmaf(acc1, inv, Bl[ch + 1]);
    o0 = (o0 > 0.f) ? o0 : 0.01f * o0;
    o1 = (o1 > 0.f) ? o1 : 0.01f * o1;
    HoutU[(size_t)n * 64 + lane] = pack2(o0, o1);
}

// ---------------------------------------------------------------------------
__global__ __launch_bounds__(256) void hw5_kernel(const uint32* __restrict__ Hu,
                                                  const float* __restrict__ PAR,
                                                  float* __restrict__ hw5) {
    int lane = threadIdx.x & 63;
    int n = blockIdx.x * 4 + (threadIdx.x >> 6);
    uint32 hb = Hu[(size_t)n * 64 + lane];
    float p = lo2f(hb) * PAR[P_W5 + 2 * lane] + hi2f(hb) * PAR[P_W5 + 2 * lane + 1];
#pragma unroll
    for (int o = 32; o; o >>= 1) p += __shfl_xor(p, o, 64);
    if (lane == 0) hw5[n] = p;
}

__global__ __launch_bounds__(256) void final_kernel(
        const float* __restrict__ hw5, const int2* __restrict__ csr,
        const void* __restrict__ eaP, const int* __restrict__ FLAG,
        const int* __restrict__ row_ptr, const float* __restrict__ PAR,
        void* __restrict__ out) {
    const int flag = FLAG[0];
    int lane = threadIdx.x & 63;
    int n = blockIdx.x * 4 + (threadIdx.x >> 6);
    int begin = __builtin_amdgcn_readfirstlane(row_ptr[n]);
    int end   = __builtin_amdgcn_readfirstlane(row_ptr[n + 1]);
    if ((unsigned)begin > EE) begin = 0;
    if ((unsigned)end > EE) end = begin;
    int deg = end - begin; if (deg < 0) deg = 0;
    float c50 = PAR[P_CVEC + 8], c51 = PAR[P_CVEC + 9];
    float ce0 = PAR[P_CVEC + 10], ce1 = PAR[P_CVEC + 11];
    float b5v = PAR[P_SC5], a5s = PAR[P_SC5 + 1];
    float hd = PAR[P_SC5 + 2] * hw5[n];

    float m = -3.4e38f;
    for (int j0 = 0; j0 < deg; j0 += 64) {
        int j = j0 + lane;
        if (j < deg) {
            int2 ce = csr[begin + j];
            int s = ((unsigned)ce.x < NV) ? ce.x : 0;
            int ei = ((unsigned)ce.y < EE) ? ce.y : 0;
            float2 ea = lde2(eaP, ei, flag);
            float L = fmaf(ea.y, c51, fmaf(ea.x, c50, fmaf(a5s, hw5[s], hd)));
            L = (L > 0.f) ? L : 0.2f * L;
            m = fmaxf(m, L);
        }
    }
#pragma unroll
    for (int o = 32; o; o >>= 1) m = fmaxf(m, __shfl_xor(m, o, 64));

    float dsum = 0.f, msum = 0.f;
    for (int j0 = 0; j0 < deg; j0 += 64) {
        int j = j0 + lane;
        if (j < deg) {
            int2 ce = csr[begin + j];
            int s = ((unsigned)ce.x < NV) ? ce.x : 0;
            int ei = ((unsigned)ce.y < EE) ? ce.y : 0;
            float2 ea = lde2(eaP, ei, flag);
            float hs5 = hw5[s];
            float L = fmaf(ea.y, c51, fmaf(ea.x, c50, fmaf(a5s, hs5, hd)));
            L = (L > 0.f) ? L : 0.2f * L;
            float ex = __expf(L - m);
            dsum += ex;
            msum = fmaf(ex, hs5 + fmaf(ea.y, ce1, ea.x * ce0), msum);
        }
    }
#pragma unroll
    for (int o = 32; o; o >>= 1) {
        dsum += __shfl_xor(dsum, o, 64);
        msum += __shfl_xor(msum, o, 64);
    }
    if (lane == 0) {
        float r = msum / (dsum + 1e-16f) + b5v;
        if (flag) ((float*)out)[n] = r;
        else      ((u16b*)out)[n] = (u16b)f2bf_bits(r);
    }
}

// ---------------------------------------------------------------------------
extern "C" void kernel_launch(void* const* d_in, const int* in_sizes, int n_in,
                              void* d_out, int out_size, void* d_ws, size_t ws_size,
                              hipStream_t stream) {
    const void* x   = d_in[0];
    const int*  ei  = (const int*)d_in[1];
    const void* ea  = d_in[2];
    const int*  cur = (const int*)d_in[3];
    const void* vge = d_in[4];
    const void* vnd = d_in[5];
    const void* pW  = d_in[6];
    const void* pb  = d_in[7];
    const void* Ws  = d_in[8];
    const void* bs  = d_in[9];
    const void* asr = d_in[10];
    const void* ads = d_in[11];
    const void* aeg = d_in[12];
    const void* Wes = d_in[13];
    const void* W5  = d_in[14];
    const void* b5  = d_in[15];
    const void* as5 = d_in[16];
    const void* ad5 = d_in[17];
    const void* ae5 = d_in[18];
    const void* We5 = d_in[19];
    (void)in_sizes; (void)n_in; (void)out_size;

    const int* e_src = ei;
    const int* e_dst = ei + EE;

    size_t off = 0;
    char* base = (char*)d_ws;
    auto carve = [&](size_t bytes) {
        void* p = base + off;
        off += (bytes + 255) & ~(size_t)255;
        return p;
    };
    int*    FLAG   = (int*)carve(256);
    float*  PAR    = (float*)carve((size_t)P_TOT * 4);
    uint32* H0     = (uint32*)carve((size_t)NV * DD * 2);
    uint32* H1     = (uint32*)carve((size_t)NV * DD * 2);
    float*  SS     = (float*)carve(NV * 4);          // contiguous with SD
    float*  SD     = (float*)carve(NV * 4);
    float*  HW5v   = (float*)carve(NV * 4);
    int*    COUNTS = (int*)carve(65536 * 4);
    int*    ROWPTR = (int*)carve(65536 * 4);
    int*    CURSOR = (int*)carve(NV * 4);
    int*    PART   = (int*)carve(256 * 4);
    int*    BOFF   = (int*)carve(256 * 4);
    int2*   CSR    = (int2*)carve((size_t)EE * 8);
    size_t need = off;

    sniff_kernel<<<1, 256, 0, stream>>>((const unsigned short*)ea, FLAG);

    if (need > ws_size) {
        // Diagnostic fallback: zeros + ws_size (MB) tag in out[0].
        zero_out_kernel<<<(NV + 255) / 256, 256, 0, stream>>>(
            d_out, FLAG, (float)(ws_size >> 20));
        return;
    }

    prep_kernel<<<64, 256, 0, stream>>>(Ws, Wes, aeg, We5, ae5, asr, ads, bs,
                                        W5, b5, as5, ad5, FLAG, PAR);
    proj_kernel<<<NV, 64, 0, stream>>>(x, pW, pb, cur, vge, vnd, FLAG, H0);

    hipMemsetAsync(COUNTS, 0, 65536 * 4, stream);
    hist_kernel<<<1024, 256, 0, stream>>>(e_dst, COUNTS);
    scan1_kernel<<<63, 256, 0, stream>>>(COUNTS, ROWPTR, PART);
    scan2_kernel<<<1, 64, 0, stream>>>(PART, BOFF, 63);
    scan3_kernel<<<63, 256, 0, stream>>>(ROWPTR, BOFF, CURSOR);
    scatter_kernel<<<1024, 256, 0, stream>>>(e_src, e_dst, CURSOR, CSR);

    for (int l = 0; l < 4; ++l) {
        hipMemsetAsync(SS, 0, (size_t)NV * 8, stream);   // SS + SD contiguous
        gemm_kernel<<<dim3(NV / 64, 2), 256, 0, stream>>>(
            H0, PAR + P_WF + l * DD * DD, PAR + P_ASRC + l * DD,
            PAR + P_ADST + l * DD, H1, SS, SD);
        agg_kernel<<<NV / 4, 256, 0, stream>>>(
            H1, SS, SD, CSR, ea, FLAG, ROWPTR, PAR, l, H0);
    }

    hw5_kernel<<<NV / 4, 256, 0, stream>>>(H0, PAR, HW5v);
    final_kernel<<<NV / 4, 256, 0, stream>>>(HW5v, CSR, ea, FLAG, ROWPTR, PAR, d_out);
}

// Round 4
// 627.982 us; speedup vs baseline: 1.3385x; 1.3385x over previous
//
#include <hip/hip_runtime.h>
#include <hip/hip_bf16.h>

// Problem constants (fixed by the reference).
#define BB   128
#define NN   500
#define NV   64000        // BB*NN nodes
#define EE   1048576      // edges
#define DD   128
#define FIN  5
#define VNN  10

typedef unsigned int   uint32;
typedef unsigned short u16b;

// fp32 param-block layout (element offsets)
#define P_WF    0          // 4*128*128
#define P_ASRC  65536      // 4*128
#define P_ADST  66048      // 4*128
#define P_WE    66560      // 4*2*128
#define P_BIAS  67584      // 4*128
#define P_W5    68096      // 128
#define P_CVEC  68224      // 12
#define P_SC5   68236      // b5, as5, ad5
#define P_TOT   68352

static __device__ __forceinline__ float bf2f(__hip_bfloat16 v) { return __bfloat162float(v); }
static __device__ __forceinline__ float lo2f(uint32 u) { return __uint_as_float(u << 16); }
static __device__ __forceinline__ float hi2f(uint32 u) { return __uint_as_float(u & 0xFFFF0000u); }
static __device__ __forceinline__ uint32 f2bf_bits(float f) {
    uint32 u = __float_as_uint(f);
    return (u + 0x7FFFu + ((u >> 16) & 1u)) >> 16;
}
static __device__ __forceinline__ uint32 pack2(float a, float b) {
    return (f2bf_bits(a) & 0xFFFFu) | (f2bf_bits(b) << 16);
}
// flag-dispatched loads (cold paths only): 1 -> fp32 container, 0 -> bf16
static __device__ __forceinline__ float ldf(const void* p, int i, int flag) {
    return flag ? ((const float*)p)[i] : bf2f(((const __hip_bfloat16*)p)[i]);
}

// ---------------------------------------------------------------------------
// dtype sniffer on edge_attr (uniform[0,1))
__global__ void sniff_kernel(const unsigned short* __restrict__ p16, int* __restrict__ FLAG) {
    __shared__ int sHigh, sZero;
    if (threadIdx.x == 0) { sHigh = 0; sZero = 0; }
    __syncthreads();
    unsigned short v = p16[2 * threadIdx.x];
    if (v >= 0x8000u) atomicOr(&sHigh, 1);
    if (v == 0)       atomicAdd(&sZero, 1);
    __syncthreads();
    if (threadIdx.x == 0) FLAG[0] = (sHigh || sZero >= 128) ? 1 : 0;
}

// fallback when workspace too small: zeros + ws_size tag in out[0]
__global__ void zero_out_kernel(void* __restrict__ out, const int* __restrict__ FLAG, float tag) {
    int i = blockIdx.x * blockDim.x + threadIdx.x;
    if (i >= NV) return;
    float v = (i == 0) ? tag : 0.f;
    if (FLAG[0]) ((float*)out)[i] = v;
    else         ((u16b*)out)[i] = (u16b)f2bf_bits(v);
}

// ---------------------------------------------------------------------------
// prep: canonicalize all weights to fp32 PAR block; attention-edge scalars.
__global__ void prep_kernel(const void* __restrict__ Ws, const void* __restrict__ Wes,
                            const void* __restrict__ aeg, const void* __restrict__ We5,
                            const void* __restrict__ ae5, const void* __restrict__ asr,
                            const void* __restrict__ ads, const void* __restrict__ bs,
                            const void* __restrict__ W5, const void* __restrict__ b5,
                            const void* __restrict__ as5, const void* __restrict__ ad5,
                            const int* __restrict__ FLAG, float* __restrict__ PAR) {
    const int flag = FLAG[0];
    int t = blockIdx.x * blockDim.x + threadIdx.x;
    for (int i = t; i < 4 * DD * DD; i += gridDim.x * blockDim.x)
        PAR[P_WF + i] = ldf(Ws, i, flag);
    if (blockIdx.x == 0) {
        for (int i = threadIdx.x; i < 512; i += 256) PAR[P_ASRC + i] = ldf(asr, i, flag);
    } else if (blockIdx.x == 1) {
        for (int i = threadIdx.x; i < 512; i += 256) PAR[P_ADST + i] = ldf(ads, i, flag);
    } else if (blockIdx.x == 2) {
        for (int i = threadIdx.x; i < 1024; i += 256) PAR[P_WE + i] = ldf(Wes, i, flag);
    } else if (blockIdx.x == 3) {
        for (int i = threadIdx.x; i < 512; i += 256) PAR[P_BIAS + i] = ldf(bs, i, flag);
    } else if (blockIdx.x == 4) {
        int tid = threadIdx.x;
        if (tid < 128) {
            PAR[P_W5 + tid] = ldf(W5, tid, flag);
        } else if (tid < 136) {
            int l = (tid - 128) >> 1, r = (tid - 128) & 1;
            float s = 0.f;
            for (int ch = 0; ch < DD; ++ch)
                s += ldf(Wes, l * 256 + r * DD + ch, flag) * ldf(aeg, l * DD + ch, flag);
            PAR[P_CVEC + l * 2 + r] = s;
        } else if (tid == 136) {
            float ae = ldf(ae5, 0, flag);
            float w0 = ldf(We5, 0, flag), w1 = ldf(We5, 1, flag);
            PAR[P_CVEC + 8] = w0 * ae; PAR[P_CVEC + 9] = w1 * ae;
            PAR[P_CVEC + 10] = w0;     PAR[P_CVEC + 11] = w1;
            PAR[P_SC5 + 0] = ldf(b5, 0, flag);
            PAR[P_SC5 + 1] = ldf(as5, 0, flag);
            PAR[P_SC5 + 2] = ldf(ad5, 0, flag);
        }
    }
}

// ---------------------------------------------------------------------------
// input projection: h0 = lrelu(x@pW + pb, .01) + vge[b] + vnd[b, curr[b]]
__global__ __launch_bounds__(256) void proj_kernel(
        const void* __restrict__ x, const void* __restrict__ pW,
        const void* __restrict__ pb, const int* __restrict__ curr,
        const void* __restrict__ vge, const void* __restrict__ vnd,
        const int* __restrict__ FLAG, uint32* __restrict__ H) {
    const int flag = FLAG[0];
    const int n = blockIdx.x * 4 + (threadIdx.x >> 6);
    const int lane = threadIdx.x & 63;
    const int b = n / NN;
    int cv = curr[b]; if ((unsigned)cv >= VNN) cv = 0;
    float xv[FIN];
#pragma unroll
    for (int k = 0; k < FIN; ++k) xv[k] = ldf(x, n * FIN + k, flag);
    const int ch = lane * 2;
    float s0 = ldf(pb, ch, flag), s1 = ldf(pb, ch + 1, flag);
#pragma unroll
    for (int k = 0; k < FIN; ++k) {
        s0 = fmaf(xv[k], ldf(pW, k * DD + ch, flag), s0);
        s1 = fmaf(xv[k], ldf(pW, k * DD + ch + 1, flag), s1);
    }
    s0 = (s0 > 0.f) ? s0 : 0.01f * s0;
    s1 = (s1 > 0.f) ? s1 : 0.01f * s1;
    s0 += ldf(vge, b * DD + ch, flag) + ldf(vnd, (b * VNN + cv) * DD + ch, flag);
    s1 += ldf(vge, b * DD + ch + 1, flag) + ldf(vnd, (b * VNN + cv) * DD + ch + 1, flag);
    H[(size_t)n * 64 + lane] = pack2(s0, s1);
}

// ---------------------------------------------------------------------------
// CSR build: histogram -> scan -> scatter (counting sort by dst)
__global__ void hist_kernel(const int* __restrict__ dst, int* __restrict__ counts) {
    for (int e = blockIdx.x * blockDim.x + threadIdx.x; e < EE; e += gridDim.x * blockDim.x) {
        int d = dst[e];
        if ((unsigned)d < NV) atomicAdd(&counts[d], 1);
    }
}

__global__ __launch_bounds__(256) void scan1_kernel(const int* __restrict__ counts,
                                                    int* __restrict__ row_ptr,
                                                    int* __restrict__ partials) {
    __shared__ int sdata[256];
    int tid = threadIdx.x;
    int4 v = ((const int4*)counts)[blockIdx.x * 256 + tid];
    int sum = v.x + v.y + v.z + v.w;
    sdata[tid] = sum;
    __syncthreads();
    int acc = sum;
    for (int off = 1; off < 256; off <<= 1) {
        int t = (tid >= off) ? sdata[tid - off] : 0;
        __syncthreads();
        acc += t;
        sdata[tid] = acc;
        __syncthreads();
    }
    int excl = acc - sum;
    int base = blockIdx.x * 1024 + tid * 4;
    int run = excl;
    if (base + 0 <= NV) row_ptr[base + 0] = run; run += v.x;
    if (base + 1 <= NV) row_ptr[base + 1] = run; run += v.y;
    if (base + 2 <= NV) row_ptr[base + 2] = run; run += v.z;
    if (base + 3 <= NV) row_ptr[base + 3] = run;
    if (tid == 255) partials[blockIdx.x] = acc;
}

__global__ __launch_bounds__(64) void scan2_kernel(const int* __restrict__ partials,
                                                   int* __restrict__ boff, int nb) {
    int lane = threadIdx.x;
    int v = (lane < nb) ? partials[lane] : 0;
    int orig = v;
#pragma unroll
    for (int off = 1; off < 64; off <<= 1) {
        int t = __shfl_up(v, off, 64);
        if (lane >= off) v += t;
    }
    boff[lane] = v - orig;
}

__global__ __launch_bounds__(256) void scan3_kernel(int* __restrict__ row_ptr,
                                                    const int* __restrict__ boff,
                                                    int* __restrict__ cursor) {
    int add = boff[blockIdx.x];
    int base = blockIdx.x * 1024 + threadIdx.x * 4;
#pragma unroll
    for (int j = 0; j < 4; ++j) {
        int i = base + j;
        if (i <= NV) {
            int r = row_ptr[i] + add;
            row_ptr[i] = r;
            if (i < NV) cursor[i] = r;
        }
    }
}

// scatter: csr_src[p]=src, csr_ea[p]=packed bf16 edge attrs (flag-converted)
__global__ void scatter_kernel(const int* __restrict__ src, const int* __restrict__ dst,
                               const void* __restrict__ eaP, const int* __restrict__ FLAG,
                               int* __restrict__ cursor, int* __restrict__ csr_src,
                               uint32* __restrict__ csr_ea) {
    const int flag = FLAG[0];
    for (int e = blockIdx.x * blockDim.x + threadIdx.x; e < EE; e += gridDim.x * blockDim.x) {
        int d = dst[e];
        if ((unsigned)d >= NV) continue;
        int p = atomicAdd(&cursor[d], 1);
        if ((unsigned)p >= EE) continue;
        int s = src[e];
        csr_src[p] = ((unsigned)s < NV) ? s : 0;
        uint32 eb;
        if (flag) {
            float2 v = ((const float2*)eaP)[e];
            eb = pack2(v.x, v.y);
        } else {
            eb = ((const uint32*)eaP)[e];
        }
        csr_ea[p] = eb;
    }
}

// ---------------------------------------------------------------------------
// GEMM: HW = H @ W. H bf16-packed, W fp32 (PAR), acc fp32, HW bf16-packed.
// Block = 64 nodes x 64 cols (gridDim.y=2), 4 waves x 16 cols.
__global__ __launch_bounds__(256) void gemm_kernel(
        const uint32* __restrict__ Hu, const float* __restrict__ Wf,
        const float* __restrict__ Asr, const float* __restrict__ Ads,
        uint32* __restrict__ HWu, float* __restrict__ ssrc, float* __restrict__ sdst) {
    __shared__ float hs[64 * 129];
    const int tid = threadIdx.x;
    const int lane = tid & 63;
    const int wave = tid >> 6;
    const int n0 = blockIdx.x * 64;
    const int chB = blockIdx.y * 64;
    const int ch0u = __builtin_amdgcn_readfirstlane(chB + wave * 16);

    {   // stage H tile (bf16 -> fp32)
        const int n = tid & 63;
        const int k0h = (tid >> 6) * 16;
        const uint4* srcp = (const uint4*)(Hu + (size_t)(n0 + n) * 64 + k0h);
        float* dp = hs + n * 129 + k0h * 2;
#pragma unroll
        for (int i = 0; i < 4; ++i) {
            uint4 v = srcp[i];
            dp[8 * i + 0] = lo2f(v.x); dp[8 * i + 1] = hi2f(v.x);
            dp[8 * i + 2] = lo2f(v.y); dp[8 * i + 3] = hi2f(v.y);
            dp[8 * i + 4] = lo2f(v.z); dp[8 * i + 5] = hi2f(v.z);
            dp[8 * i + 6] = lo2f(v.w); dp[8 * i + 7] = hi2f(v.w);
        }
    }
    __syncthreads();

    float acc[16];
#pragma unroll
    for (int j = 0; j < 16; ++j) acc[j] = 0.f;

    const float* hrow = hs + lane * 129;
#pragma unroll 4
    for (int k = 0; k < DD; ++k) {
        float hk = hrow[k];
        const float* wk = Wf + k * DD + ch0u;   // wave-uniform -> s_load
#pragma unroll
        for (int j = 0; j < 16; ++j) acc[j] = fmaf(hk, wk[j], acc[j]);
    }

    float psrc = 0.f, pdst = 0.f;
#pragma unroll
    for (int j = 0; j < 16; ++j) {
        psrc = fmaf(acc[j], Asr[ch0u + j], psrc);
        pdst = fmaf(acc[j], Ads[ch0u + j], pdst);
    }
    atomicAdd(&ssrc[n0 + lane], psrc);
    atomicAdd(&sdst[n0 + lane], pdst);

    __syncthreads();
#pragma unroll
    for (int j = 0; j < 16; ++j)
        hs[lane * 65 + wave * 16 + j] = acc[j];
    __syncthreads();
#pragma unroll
    for (int i = 0; i < 2; ++i) {
        int flat = i * 2048 + tid * 8;
        int n = flat >> 6, c = flat & 63;
        const float* p = hs + n * 65 + c;
        uint4 v;
        v.x = pack2(p[0], p[1]); v.y = pack2(p[2], p[3]);
        v.z = pack2(p[4], p[5]); v.w = pack2(p[6], p[7]);
        *(uint4*)(HWu + (size_t)(n0 + n) * 64 + (chB + c) / 2) = v;
    }
}

// ---------------------------------------------------------------------------
// Hidden-layer attention + aggregation. One wave per dst node.
// Pass 1 (lane-parallel): segment max. Pass 2 (serial, x4 unrolled for MLP):
// ex=exp(L-m); acc += ex*(hw[src]+e); out = lrelu(acc/(sum+1e-16)+b, .01).
__global__ __launch_bounds__(256) void agg_kernel(
        const uint32* __restrict__ HWu, const float* __restrict__ ssrc,
        const float* __restrict__ sdst, const int* __restrict__ csr_src,
        const uint32* __restrict__ csr_ea, const int* __restrict__ row_ptr,
        const float* __restrict__ PAR, int layer, uint32* __restrict__ HoutU) {
    const int lane = threadIdx.x & 63;
    const int n = blockIdx.x * 4 + (threadIdx.x >> 6);
    const int begin = __builtin_amdgcn_readfirstlane(row_ptr[n]);
    const int deg   = __builtin_amdgcn_readfirstlane(row_ptr[n + 1]) - begin;
    const float c0 = PAR[P_CVEC + 2 * layer], c1 = PAR[P_CVEC + 2 * layer + 1];
    const float sd = sdst[n];

    float m = -3.4e38f;
    for (int j0 = 0; j0 < deg; j0 += 64) {
        int j = j0 + lane;
        if (j < deg) {
            int s = csr_src[begin + j];          // coalesced
            uint32 eb = csr_ea[begin + j];       // coalesced
            float L = fmaf(hi2f(eb), c1, fmaf(lo2f(eb), c0, ssrc[s] + sd));
            L = (L > 0.f) ? L : 0.2f * L;
            m = fmaxf(m, L);
        }
    }
#pragma unroll
    for (int o = 32; o; o >>= 1) m = fmaxf(m, __shfl_xor(m, o, 64));

    const int ch = lane * 2;
    const float* WEl = PAR + P_WE + layer * 256;
    const float w0x = WEl[ch],      w0y = WEl[ch + 1];
    const float w1x = WEl[DD + ch], w1y = WEl[DD + ch + 1];

    float dsum = 0.f, acc0 = 0.f, acc1 = 0.f;
    int jj = 0;
    for (; jj + 4 <= deg; jj += 4) {
        // batch loads: 4 edges' metadata + 4 coalesced 256B rows in flight
        int s0 = csr_src[begin + jj + 0];
        int s1 = csr_src[begin + jj + 1];
        int s2 = csr_src[begin + jj + 2];
        int s3 = csr_src[begin + jj + 3];
        uint32 e0 = csr_ea[begin + jj + 0];
        uint32 e1 = csr_ea[begin + jj + 1];
        uint32 e2 = csr_ea[begin + jj + 2];
        uint32 e3 = csr_ea[begin + jj + 3];
        float g0 = ssrc[s0], g1 = ssrc[s1], g2 = ssrc[s2], g3 = ssrc[s3];
        uint32 h0 = HWu[(size_t)s0 * 64 + lane];
        uint32 h1 = HWu[(size_t)s1 * 64 + lane];
        uint32 h2 = HWu[(size_t)s2 * 64 + lane];
        uint32 h3 = HWu[(size_t)s3 * 64 + lane];

        float L0 = fmaf(hi2f(e0), c1, fmaf(lo2f(e0), c0, g0 + sd));
        float L1 = fmaf(hi2f(e1), c1, fmaf(lo2f(e1), c0, g1 + sd));
        float L2 = fmaf(hi2f(e2), c1, fmaf(lo2f(e2), c0, g2 + sd));
        float L3 = fmaf(hi2f(e3), c1, fmaf(lo2f(e3), c0, g3 + sd));
        L0 = (L0 > 0.f) ? L0 : 0.2f * L0;
        L1 = (L1 > 0.f) ? L1 : 0.2f * L1;
        L2 = (L2 > 0.f) ? L2 : 0.2f * L2;
        L3 = (L3 > 0.f) ? L3 : 0.2f * L3;
        float x0 = __expf(L0 - m), x1 = __expf(L1 - m);
        float x2 = __expf(L2 - m), x3 = __expf(L3 - m);
        dsum += (x0 + x1) + (x2 + x3);
        acc0 = fmaf(x0, lo2f(h0) + fmaf(hi2f(e0), w1x, lo2f(e0) * w0x), acc0);
        acc1 = fmaf(x0, hi2f(h0) + fmaf(hi2f(e0), w1y, lo2f(e0) * w0y), acc1);
        acc0 = fmaf(x1, lo2f(h1) + fmaf(hi2f(e1), w1x, lo2f(e1) * w0x), acc0);
        acc1 = fmaf(x1, hi2f(h1) + fmaf(hi2f(e1), w1y, lo2f(e1) * w0y), acc1);
        acc0 = fmaf(x2, lo2f(h2) + fmaf(hi2f(e2), w1x, lo2f(e2) * w0x), acc0);
        acc1 = fmaf(x2, hi2f(h2) + fmaf(hi2f(e2), w1y, lo2f(e2) * w0y), acc1);
        acc0 = fmaf(x3, lo2f(h3) + fmaf(hi2f(e3), w1x, lo2f(e3) * w0x), acc0);
        acc1 = fmaf(x3, hi2f(h3) + fmaf(hi2f(e3), w1y, lo2f(e3) * w0y), acc1);
    }
    for (; jj < deg; ++jj) {
        int s = csr_src[begin + jj];
        uint32 eb = csr_ea[begin + jj];
        float L = fmaf(hi2f(eb), c1, fmaf(lo2f(eb), c0, ssrc[s] + sd));
        L = (L > 0.f) ? L : 0.2f * L;
        float ex = __expf(L - m);
        dsum += ex;
        uint32 hb = HWu[(size_t)s * 64 + lane];
        acc0 = fmaf(ex, lo2f(hb) + fmaf(hi2f(eb), w1x, lo2f(eb) * w0x), acc0);
        acc1 = fmaf(ex, hi2f(hb) + fmaf(hi2f(eb), w1y, lo2f(eb) * w0y), acc1);
    }
    const float inv = 1.f / (dsum + 1e-16f);
    const float* Bl = PAR + P_BIAS + layer * DD;
    float o0 = fmaf(acc0, inv, Bl[ch]);
    float o1 = fmaf(acc1, inv, Bl[ch + 1]);
    o0 = (o0 > 0.f) ? o0 : 0.01f * o0;
    o1 = (o1 > 0.f) ? o1 : 0.01f * o1;
    HoutU[(size_t)n * 64 + lane] = pack2(o0, o1);
}

// ---------------------------------------------------------------------------
__global__ __launch_bounds__(256) void hw5_kernel(const uint32* __restrict__ Hu,
                                                  const float* __restrict__ PAR,
                                                  float* __restrict__ hw5) {
    int lane = threadIdx.x & 63;
    int n = blockIdx.x * 4 + (threadIdx.x >> 6);
    uint32 hb = Hu[(size_t)n * 64 + lane];
    float p = lo2f(hb) * PAR[P_W5 + 2 * lane] + hi2f(hb) * PAR[P_W5 + 2 * lane + 1];
#pragma unroll
    for (int o = 32; o; o >>= 1) p += __shfl_xor(p, o, 64);
    if (lane == 0) hw5[n] = p;
}

__global__ __launch_bounds__(256) void final_kernel(
        const float* __restrict__ hw5, const int* __restrict__ csr_src,
        const uint32* __restrict__ csr_ea, const int* __restrict__ row_ptr,
        const float* __restrict__ PAR, const int* __restrict__ FLAG,
        void* __restrict__ out) {
    const int flag = FLAG[0];
    int lane = threadIdx.x & 63;
    int n = blockIdx.x * 4 + (threadIdx.x >> 6);
    int begin = __builtin_amdgcn_readfirstlane(row_ptr[n]);
    int deg   = __builtin_amdgcn_readfirstlane(row_ptr[n + 1]) - begin;
    float c50 = PAR[P_CVEC + 8], c51 = PAR[P_CVEC + 9];
    float ce0 = PAR[P_CVEC + 10], ce1 = PAR[P_CVEC + 11];
    float b5v = PAR[P_SC5], a5s = PAR[P_SC5 + 1];
    float hd = PAR[P_SC5 + 2] * hw5[n];

    float m = -3.4e38f;
    for (int j0 = 0; j0 < deg; j0 += 64) {
        int j = j0 + lane;
        if (j < deg) {
            int s = csr_src[begin + j];
            uint32 eb = csr_ea[begin + j];
            float L = fmaf(hi2f(eb), c51, fmaf(lo2f(eb), c50, fmaf(a5s, hw5[s], hd)));
            L = (L > 0.f) ? L : 0.2f * L;
            m = fmaxf(m, L);
        }
    }
#pragma unroll
    for (int o = 32; o; o >>= 1) m = fmaxf(m, __shfl_xor(m, o, 64));

    float dsum = 0.f, msum = 0.f;
    for (int j0 = 0; j0 < deg; j0 += 64) {
        int j = j0 + lane;
        if (j < deg) {
            int s = csr_src[begin + j];
            uint32 eb = csr_ea[begin + j];
            float hs5 = hw5[s];
            float L = fmaf(hi2f(eb), c51, fmaf(lo2f(eb), c50, fmaf(a5s, hs5, hd)));
            L = (L > 0.f) ? L : 0.2f * L;
            float ex = __expf(L - m);
            dsum += ex;
            msum = fmaf(ex, hs5 + fmaf(hi2f(eb), ce1, lo2f(eb) * ce0), msum);
        }
    }
#pragma unroll
    for (int o = 32; o; o >>= 1) {
        dsum += __shfl_xor(dsum, o, 64);
        msum += __shfl_xor(msum, o, 64);
    }
    if (lane == 0) {
        float r = msum / (dsum + 1e-16f) + b5v;
        if (flag) ((float*)out)[n] = r;
        else      ((u16b*)out)[n] = (u16b)f2bf_bits(r);
    }
}

// ---------------------------------------------------------------------------
extern "C" void kernel_launch(void* const* d_in, const int* in_sizes, int n_in,
                              void* d_out, int out_size, void* d_ws, size_t ws_size,
                              hipStream_t stream) {
    const void* x   = d_in[0];
    const int*  ei  = (const int*)d_in[1];
    const void* ea  = d_in[2];
    const int*  cur = (const int*)d_in[3];
    const void* vge = d_in[4];
    const void* vnd = d_in[5];
    const void* pW  = d_in[6];
    const void* pb  = d_in[7];
    const void* Ws  = d_in[8];
    const void* bs  = d_in[9];
    const void* asr = d_in[10];
    const void* ads = d_in[11];
    const void* aeg = d_in[12];
    const void* Wes = d_in[13];
    const void* W5  = d_in[14];
    const void* b5  = d_in[15];
    const void* as5 = d_in[16];
    const void* ad5 = d_in[17];
    const void* ae5 = d_in[18];
    const void* We5 = d_in[19];
    (void)in_sizes; (void)n_in; (void)out_size;

    const int* e_src = ei;
    const int* e_dst = ei + EE;

    size_t off = 0;
    char* base = (char*)d_ws;
    auto carve = [&](size_t bytes) {
        void* p = base + off;
        off += (bytes + 255) & ~(size_t)255;
        return p;
    };
    int*    FLAG   = (int*)carve(256);
    float*  PAR    = (float*)carve((size_t)P_TOT * 4);
    uint32* H0     = (uint32*)carve((size_t)NV * DD * 2);
    uint32* H1     = (uint32*)carve((size_t)NV * DD * 2);
    float*  SS     = (float*)carve(NV * 4);          // contiguous with SD
    float*  SD     = (float*)carve(NV * 4);
    float*  HW5v   = (float*)carve(NV * 4);
    int*    COUNTS = (int*)carve(65536 * 4);
    int*    ROWPTR = (int*)carve(65536 * 4);
    int*    CURSOR = (int*)carve(NV * 4);
    int*    PART   = (int*)carve(256 * 4);
    int*    BOFF   = (int*)carve(256 * 4);
    int*    CSRS   = (int*)carve((size_t)EE * 4);
    uint32* CSREA  = (uint32*)carve((size_t)EE * 4);
    size_t need = off;

    sniff_kernel<<<1, 256, 0, stream>>>((const unsigned short*)ea, FLAG);

    if (need > ws_size) {
        zero_out_kernel<<<(NV + 255) / 256, 256, 0, stream>>>(
            d_out, FLAG, (float)(ws_size >> 20));
        return;
    }

    prep_kernel<<<64, 256, 0, stream>>>(Ws, Wes, aeg, We5, ae5, asr, ads, bs,
                                        W5, b5, as5, ad5, FLAG, PAR);
    proj_kernel<<<NV / 4, 256, 0, stream>>>(x, pW, pb, cur, vge, vnd, FLAG, H0);

    hipMemsetAsync(COUNTS, 0, 65536 * 4, stream);
    hist_kernel<<<1024, 256, 0, stream>>>(e_dst, COUNTS);
    scan1_kernel<<<63, 256, 0, stream>>>(COUNTS, ROWPTR, PART);
    scan2_kernel<<<1, 64, 0, stream>>>(PART, BOFF, 63);
    scan3_kernel<<<63, 256, 0, stream>>>(ROWPTR, BOFF, CURSOR);
    scatter_kernel<<<1024, 256, 0, stream>>>(e_src, e_dst, ea, FLAG, CURSOR, CSRS, CSREA);

    for (int l = 0; l < 4; ++l) {
        hipMemsetAsync(SS, 0, (size_t)NV * 8, stream);   // SS + SD contiguous
        gemm_kernel<<<dim3(NV / 64, 2), 256, 0, stream>>>(
            H0, PAR + P_WF + l * DD * DD, PAR + P_ASRC + l * DD,
            PAR + P_ADST + l * DD, H1, SS, SD);
        agg_kernel<<<NV / 4, 256, 0, stream>>>(
            H1, SS, SD, CSRS, CSREA, ROWPTR, PAR, l, H0);
    }

    hw5_kernel<<<NV / 4, 256, 0, stream>>>(H0, PAR, HW5v);
    final_kernel<<<NV / 4, 256, 0, stream>>>(HW5v, CSRS, CSREA, ROWPTR, PAR, FLAG, d_out);
}

// Round 5
// 580.058 us; speedup vs baseline: 1.4491x; 1.0826x over previous
//
#include <hip/hip_runtime.h>
#include <hip/hip_bf16.h>

// Problem constants (fixed by the reference).
#define BB   128
#define NN   500
#define NV   64000        // BB*NN nodes
#define EE   1048576      // edges
#define DD   128
#define FIN  5
#define VNN  10

typedef unsigned int   uint32;
typedef unsigned short u16b;
typedef __attribute__((ext_vector_type(8))) short short8;   // 8 bf16 (4 VGPRs)
typedef __attribute__((ext_vector_type(4))) float float4v;  // MFMA C/D

// fp32 param-block layout (element offsets)
#define P_ASRC  0          // 4*128
#define P_ADST  512        // 4*128
#define P_WE    1024       // 4*2*128
#define P_BIAS  2048       // 4*128
#define P_W5    2560       // 128
#define P_CVEC  2688       // 12
#define P_SC5   2700       // b5, as5, ad5
#define P_TOT   2816

static __device__ __forceinline__ float bf2f(__hip_bfloat16 v) { return __bfloat162float(v); }
static __device__ __forceinline__ float lo2f(uint32 u) { return __uint_as_float(u << 16); }
static __device__ __forceinline__ float hi2f(uint32 u) { return __uint_as_float(u & 0xFFFF0000u); }
static __device__ __forceinline__ uint32 f2bf_bits(float f) {
    uint32 u = __float_as_uint(f);
    return (u + 0x7FFFu + ((u >> 16) & 1u)) >> 16;
}
static __device__ __forceinline__ uint32 pack2(float a, float b) {
    return (f2bf_bits(a) & 0xFFFFu) | (f2bf_bits(b) << 16);
}
// flag-dispatched loads (cold paths only): 1 -> fp32 container, 0 -> bf16
static __device__ __forceinline__ float ldf(const void* p, int i, int flag) {
    return flag ? ((const float*)p)[i] : bf2f(((const __hip_bfloat16*)p)[i]);
}

// ---------------------------------------------------------------------------
// dtype sniffer on edge_attr (uniform[0,1))
__global__ void sniff_kernel(const unsigned short* __restrict__ p16, int* __restrict__ FLAG) {
    __shared__ int sHigh, sZero;
    if (threadIdx.x == 0) { sHigh = 0; sZero = 0; }
    __syncthreads();
    unsigned short v = p16[2 * threadIdx.x];
    if (v >= 0x8000u) atomicOr(&sHigh, 1);
    if (v == 0)       atomicAdd(&sZero, 1);
    __syncthreads();
    if (threadIdx.x == 0) FLAG[0] = (sHigh || sZero >= 128) ? 1 : 0;
}

// fallback when workspace too small: zeros + ws_size tag in out[0]
__global__ void zero_out_kernel(void* __restrict__ out, const int* __restrict__ FLAG, float tag) {
    int i = blockIdx.x * blockDim.x + threadIdx.x;
    if (i >= NV) return;
    float v = (i == 0) ? tag : 0.f;
    if (FLAG[0]) ((float*)out)[i] = v;
    else         ((u16b*)out)[i] = (u16b)f2bf_bits(v);
}

// ---------------------------------------------------------------------------
// prep: small fp32 params + attention-edge scalars
__global__ void prep_kernel(const void* __restrict__ Wes, const void* __restrict__ aeg,
                            const void* __restrict__ We5, const void* __restrict__ ae5,
                            const void* __restrict__ asr, const void* __restrict__ ads,
                            const void* __restrict__ bs, const void* __restrict__ W5,
                            const void* __restrict__ b5, const void* __restrict__ as5,
                            const void* __restrict__ ad5, const int* __restrict__ FLAG,
                            float* __restrict__ PAR) {
    const int flag = FLAG[0];
    if (blockIdx.x == 0) {
        for (int i = threadIdx.x; i < 512; i += 256) PAR[P_ASRC + i] = ldf(asr, i, flag);
    } else if (blockIdx.x == 1) {
        for (int i = threadIdx.x; i < 512; i += 256) PAR[P_ADST + i] = ldf(ads, i, flag);
    } else if (blockIdx.x == 2) {
        for (int i = threadIdx.x; i < 1024; i += 256) PAR[P_WE + i] = ldf(Wes, i, flag);
    } else if (blockIdx.x == 3) {
        for (int i = threadIdx.x; i < 512; i += 256) PAR[P_BIAS + i] = ldf(bs, i, flag);
    } else if (blockIdx.x == 4) {
        int tid = threadIdx.x;
        if (tid < 128) {
            PAR[P_W5 + tid] = ldf(W5, tid, flag);
        } else if (tid < 136) {
            int l = (tid - 128) >> 1, r = (tid - 128) & 1;
            float s = 0.f;
            for (int ch = 0; ch < DD; ++ch)
                s += ldf(Wes, l * 256 + r * DD + ch, flag) * ldf(aeg, l * DD + ch, flag);
            PAR[P_CVEC + l * 2 + r] = s;
        } else if (tid == 136) {
            float ae = ldf(ae5, 0, flag);
            float w0 = ldf(We5, 0, flag), w1 = ldf(We5, 1, flag);
            PAR[P_CVEC + 8] = w0 * ae; PAR[P_CVEC + 9] = w1 * ae;
            PAR[P_CVEC + 10] = w0;     PAR[P_CVEC + 11] = w1;
            PAR[P_SC5 + 0] = ldf(b5, 0, flag);
            PAR[P_SC5 + 1] = ldf(as5, 0, flag);
            PAR[P_SC5 + 2] = ldf(ad5, 0, flag);
        }
    }
}

// ---------------------------------------------------------------------------
// prepack W (4 layers, 128x128) into MFMA B-fragment layout (bf16):
// fragment f = l*32 + kblk*8 + nchunk; lane holds B[k=kblk*32+quad*8+j][n=nchunk*16+(lane&15)]
// WB element offset = f*512 + lane*8 + j  -> per-lane contiguous 16B.
__global__ __launch_bounds__(256) void prepack_kernel(const void* __restrict__ Ws,
                                                      const int* __restrict__ FLAG,
                                                      u16b* __restrict__ WB) {
    const int flag = FLAG[0];
    int t = blockIdx.x * 256 + threadIdx.x;   // 8192 threads
    int lane = t & 63;
    int frag = t >> 6;                        // l*32 + kblk*8 + nchunk
    int nchunk = frag & 7, kblk = (frag >> 3) & 3, l = frag >> 5;
    int n = nchunk * 16 + (lane & 15);
    int kbase = kblk * 32 + (lane >> 4) * 8;
#pragma unroll
    for (int j = 0; j < 8; ++j) {
        int idx = l * 16384 + (kbase + j) * 128 + n;
        u16b bits = flag ? (u16b)f2bf_bits(((const float*)Ws)[idx])
                         : ((const u16b*)Ws)[idx];
        WB[(size_t)t * 8 + j] = bits;
    }
}

// ---------------------------------------------------------------------------
// input projection: h0 = lrelu(x@pW + pb, .01) + vge[b] + vnd[b, curr[b]]
__global__ __launch_bounds__(256) void proj_kernel(
        const void* __restrict__ x, const void* __restrict__ pW,
        const void* __restrict__ pb, const int* __restrict__ curr,
        const void* __restrict__ vge, const void* __restrict__ vnd,
        const int* __restrict__ FLAG, uint32* __restrict__ H) {
    const int flag = FLAG[0];
    const int n = blockIdx.x * 4 + (threadIdx.x >> 6);
    const int lane = threadIdx.x & 63;
    const int b = n / NN;
    int cv = curr[b]; if ((unsigned)cv >= VNN) cv = 0;
    float xv[FIN];
#pragma unroll
    for (int k = 0; k < FIN; ++k) xv[k] = ldf(x, n * FIN + k, flag);
    const int ch = lane * 2;
    float s0 = ldf(pb, ch, flag), s1 = ldf(pb, ch + 1, flag);
#pragma unroll
    for (int k = 0; k < FIN; ++k) {
        s0 = fmaf(xv[k], ldf(pW, k * DD + ch, flag), s0);
        s1 = fmaf(xv[k], ldf(pW, k * DD + ch + 1, flag), s1);
    }
    s0 = (s0 > 0.f) ? s0 : 0.01f * s0;
    s1 = (s1 > 0.f) ? s1 : 0.01f * s1;
    s0 += ldf(vge, b * DD + ch, flag) + ldf(vnd, (b * VNN + cv) * DD + ch, flag);
    s1 += ldf(vge, b * DD + ch + 1, flag) + ldf(vnd, (b * VNN + cv) * DD + ch + 1, flag);
    H[(size_t)n * 64 + lane] = pack2(s0, s1);
}

// ---------------------------------------------------------------------------
// CSR build: histogram -> scan -> scatter (counting sort by dst)
__global__ __launch_bounds__(256) void hist_kernel(const int* __restrict__ dst,
                                                   int* __restrict__ counts) {
    int e = blockIdx.x * 256 + threadIdx.x;   // exactly EE threads
    int d = dst[e];
    if ((unsigned)d < NV) atomicAdd(&counts[d], 1);
}

__global__ __launch_bounds__(256) void scan1_kernel(const int* __restrict__ counts,
                                                    int* __restrict__ row_ptr,
                                                    int* __restrict__ partials) {
    __shared__ int sdata[256];
    int tid = threadIdx.x;
    int4 v = ((const int4*)counts)[blockIdx.x * 256 + tid];
    int sum = v.x + v.y + v.z + v.w;
    sdata[tid] = sum;
    __syncthreads();
    int acc = sum;
    for (int off = 1; off < 256; off <<= 1) {
        int t = (tid >= off) ? sdata[tid - off] : 0;
        __syncthreads();
        acc += t;
        sdata[tid] = acc;
        __syncthreads();
    }
    int excl = acc - sum;
    int base = blockIdx.x * 1024 + tid * 4;
    int run = excl;
    if (base + 0 <= NV) row_ptr[base + 0] = run; run += v.x;
    if (base + 1 <= NV) row_ptr[base + 1] = run; run += v.y;
    if (base + 2 <= NV) row_ptr[base + 2] = run; run += v.z;
    if (base + 3 <= NV) row_ptr[base + 3] = run;
    if (tid == 255) partials[blockIdx.x] = acc;
}

__global__ __launch_bounds__(64) void scan2_kernel(const int* __restrict__ partials,
                                                   int* __restrict__ boff, int nb) {
    int lane = threadIdx.x;
    int v = (lane < nb) ? partials[lane] : 0;
    int orig = v;
#pragma unroll
    for (int off = 1; off < 64; off <<= 1) {
        int t = __shfl_up(v, off, 64);
        if (lane >= off) v += t;
    }
    boff[lane] = v - orig;
}

__global__ __launch_bounds__(256) void scan3_kernel(int* __restrict__ row_ptr,
                                                    const int* __restrict__ boff,
                                                    int* __restrict__ cursor) {
    int add = boff[blockIdx.x];
    int base = blockIdx.x * 1024 + threadIdx.x * 4;
#pragma unroll
    for (int j = 0; j < 4; ++j) {
        int i = base + j;
        if (i <= NV) {
            int r = row_ptr[i] + add;
            row_ptr[i] = r;
            if (i < NV) cursor[i] = r;
        }
    }
}

// scatter: one int2 {src, packed-bf16 ea} per edge, fully edge-parallel
__global__ __launch_bounds__(256) void scatter_kernel(
        const int* __restrict__ src, const int* __restrict__ dst,
        const void* __restrict__ eaP, const int* __restrict__ FLAG,
        int* __restrict__ cursor, int2* __restrict__ csr) {
    const int flag = FLAG[0];
    int e = blockIdx.x * 256 + threadIdx.x;   // exactly EE threads
    int d = dst[e];
    if ((unsigned)d >= NV) return;
    uint32 eb;
    if (flag) {
        float2 v = ((const float2*)eaP)[e];
        eb = pack2(v.x, v.y);
    } else {
        eb = ((const uint32*)eaP)[e];
    }
    int s = src[e];
    if ((unsigned)s >= NV) s = 0;
    int p = atomicAdd(&cursor[d], 1);
    if ((unsigned)p < EE) csr[p] = make_int2(s, (int)eb);
}

// ---------------------------------------------------------------------------
// MFMA GEMM: HW = H @ W (bf16 in, fp32 acc, bf16 out) + fused attention dots.
// Block = 64 nodes x 64 cols (gridDim.y=2 halves). Wave w: nodes [n0+16w, +16).
// 16x16x32 bf16 MFMA; A direct from H rows, B from prepacked WB fragments.
__global__ __launch_bounds__(256) void gemm_kernel(
        const uint32* __restrict__ Hu, const u16b* __restrict__ WBl,
        const float* __restrict__ PAR, uint32* __restrict__ HWu,
        float* __restrict__ ssrc, float* __restrict__ sdst, int chB) {
    __shared__ float hs[64 * 65];
    const int tid = threadIdx.x;
    const int lane = tid & 63;
    const int wave = tid >> 6;
    const int quad = lane >> 4;
    const int n0 = blockIdx.x * 64;
    const int m = n0 + wave * 16 + (lane & 15);

    // A fragments: H[m][k], k-block of 32; lane&15=m-offset, quad*8+j=k-offset
    const u16b* hrow = (const u16b*)Hu + (size_t)m * 128;
    short8 a0 = *(const short8*)(hrow + 0 * 32 + quad * 8);
    short8 a1 = *(const short8*)(hrow + 1 * 32 + quad * 8);
    short8 a2 = *(const short8*)(hrow + 2 * 32 + quad * 8);
    short8 a3 = *(const short8*)(hrow + 3 * 32 + quad * 8);

    const int nch0 = (chB >> 4);   // first nchunk of this half (0 or 4)
#pragma unroll
    for (int nt = 0; nt < 4; ++nt) {
        const u16b* bbase = WBl + ((size_t)(nch0 + nt) * 512 + lane * 8);
        short8 b0 = *(const short8*)(bbase + 0 * 8 * 512);
        short8 b1 = *(const short8*)(bbase + 1 * 8 * 512);
        short8 b2 = *(const short8*)(bbase + 2 * 8 * 512);
        short8 b3 = *(const short8*)(bbase + 3 * 8 * 512);
        float4v acc = {0.f, 0.f, 0.f, 0.f};
        acc = __builtin_amdgcn_mfma_f32_16x16x32_bf16(a0, b0, acc, 0, 0, 0);
        acc = __builtin_amdgcn_mfma_f32_16x16x32_bf16(a1, b1, acc, 0, 0, 0);
        acc = __builtin_amdgcn_mfma_f32_16x16x32_bf16(a2, b2, acc, 0, 0, 0);
        acc = __builtin_amdgcn_mfma_f32_16x16x32_bf16(a3, b3, acc, 0, 0, 0);
        // D[row=quad*4+reg][col=lane&15] -> LDS
#pragma unroll
        for (int r = 0; r < 4; ++r)
            hs[(wave * 16 + quad * 4 + r) * 65 + nt * 16 + (lane & 15)] = acc[r];
    }
    __syncthreads();

    // attention dots from LDS: thread t -> node (t&63), col group (t>>6)
    {
        const int mn = tid & 63, cg = tid >> 6;
        const float* Asr = PAR + P_ASRC;   // layer offset folded by caller
        const float* Ads = PAR + P_ADST;
        float ps = 0.f, pd = 0.f;
#pragma unroll
        for (int j = 0; j < 16; ++j) {
            float v = hs[mn * 65 + cg * 16 + j];
            ps = fmaf(v, Asr[chB + cg * 16 + j], ps);
            pd = fmaf(v, Ads[chB + cg * 16 + j], pd);
        }
        atomicAdd(&ssrc[n0 + mn], ps);
        atomicAdd(&sdst[n0 + mn], pd);
    }

    // bf16 pack + coalesced store
#pragma unroll
    for (int i = 0; i < 2; ++i) {
        int flat = i * 2048 + tid * 8;
        int n = flat >> 6, c = flat & 63;
        const float* p = hs + n * 65 + c;
        uint4 v;
        v.x = pack2(p[0], p[1]); v.y = pack2(p[2], p[3]);
        v.z = pack2(p[4], p[5]); v.w = pack2(p[6], p[7]);
        *(uint4*)(HWu + (size_t)(n0 + n) * 64 + (chB + c) / 2) = v;
    }
}

// ---------------------------------------------------------------------------
// Hidden-layer attention + aggregation. One wave per dst node.
__global__ __launch_bounds__(256) void agg_kernel(
        const uint32* __restrict__ HWu, const float* __restrict__ ssrc,
        const float* __restrict__ sdst, const int2* __restrict__ csr,
        const int* __restrict__ row_ptr, const float* __restrict__ PAR,
        int layer, uint32* __restrict__ HoutU) {
    const int lane = threadIdx.x & 63;
    const int n = blockIdx.x * 4 + (threadIdx.x >> 6);
    const int begin = __builtin_amdgcn_readfirstlane(row_ptr[n]);
    const int deg   = __builtin_amdgcn_readfirstlane(row_ptr[n + 1]) - begin;
    const float c0 = PAR[P_CVEC + 2 * layer], c1 = PAR[P_CVEC + 2 * layer + 1];
    const float sd = sdst[n];

    float m = -3.4e38f;
    for (int j0 = 0; j0 < deg; j0 += 64) {
        int j = j0 + lane;
        if (j < deg) {
            int2 ce = csr[begin + j];
            uint32 eb = (uint32)ce.y;
            float L = fmaf(hi2f(eb), c1, fmaf(lo2f(eb), c0, ssrc[ce.x] + sd));
            L = (L > 0.f) ? L : 0.2f * L;
            m = fmaxf(m, L);
        }
    }
#pragma unroll
    for (int o = 32; o; o >>= 1) m = fmaxf(m, __shfl_xor(m, o, 64));

    const int ch = lane * 2;
    const float* WEl = PAR + P_WE + layer * 256;
    const float w0x = WEl[ch],      w0y = WEl[ch + 1];
    const float w1x = WEl[DD + ch], w1y = WEl[DD + ch + 1];

    float dsum = 0.f, acc0 = 0.f, acc1 = 0.f;
    int jj = 0;
    for (; jj + 8 <= deg; jj += 8) {
        int2 ce[8];
        float g[8];
        uint32 hrow[8];
#pragma unroll
        for (int q = 0; q < 8; ++q) ce[q] = csr[begin + jj + q];
#pragma unroll
        for (int q = 0; q < 8; ++q) g[q] = ssrc[ce[q].x];
#pragma unroll
        for (int q = 0; q < 8; ++q) hrow[q] = HWu[(size_t)ce[q].x * 64 + lane];
#pragma unroll
        for (int q = 0; q < 8; ++q) {
            uint32 eb = (uint32)ce[q].y;
            float L = fmaf(hi2f(eb), c1, fmaf(lo2f(eb), c0, g[q] + sd));
            L = (L > 0.f) ? L : 0.2f * L;
            float ex = __expf(L - m);
            dsum += ex;
            acc0 = fmaf(ex, lo2f(hrow[q]) + fmaf(hi2f(eb), w1x, lo2f(eb) * w0x), acc0);
            acc1 = fmaf(ex, hi2f(hrow[q]) + fmaf(hi2f(eb), w1y, lo2f(eb) * w0y), acc1);
        }
    }
    for (; jj < deg; ++jj) {
        int2 ce = csr[begin + jj];
        uint32 eb = (uint32)ce.y;
        float L = fmaf(hi2f(eb), c1, fmaf(lo2f(eb), c0, ssrc[ce.x] + sd));
        L = (L > 0.f) ? L : 0.2f * L;
        float ex = __expf(L - m);
        dsum += ex;
        uint32 hb = HWu[(size_t)ce.x * 64 + lane];
        acc0 = fmaf(ex, lo2f(hb) + fmaf(hi2f(eb), w1x, lo2f(eb) * w0x), acc0);
        acc1 = fmaf(ex, hi2f(hb) + fmaf(hi2f(eb), w1y, lo2f(eb) * w0y), acc1);
    }
    const float inv = 1.f / (dsum + 1e-16f);
    const float* Bl = PAR + P_BIAS + layer * DD;
    float o0 = fmaf(acc0, inv, Bl[ch]);
    float o1 = fmaf(acc1, inv, Bl[ch + 1]);
    o0 = (o0 > 0.f) ? o0 : 0.01f * o0;
    o1 = (o1 > 0.f) ? o1 : 0.01f * o1;
    HoutU[(size_t)n * 64 + lane] = pack2(o0, o1);
}

// ---------------------------------------------------------------------------
__global__ __launch_bounds__(256) void hw5_kernel(const uint32* __restrict__ Hu,
                                                  const float* __restrict__ PAR,
                                                  float* __restrict__ hw5) {
    int lane = threadIdx.x & 63;
    int n = blockIdx.x * 4 + (threadIdx.x >> 6);
    uint32 hb = Hu[(size_t)n * 64 + lane];
    float p = lo2f(hb) * PAR[P_W5 + 2 * lane] + hi2f(hb) * PAR[P_W5 + 2 * lane + 1];
#pragma unroll
    for (int o = 32; o; o >>= 1) p += __shfl_xor(p, o, 64);
    if (lane == 0) hw5[n] = p;
}

__global__ __launch_bounds__(256) void final_kernel(
        const float* __restrict__ hw5, const int2* __restrict__ csr,
        const int* __restrict__ row_ptr, const float* __restrict__ PAR,
        const int* __restrict__ FLAG, void* __restrict__ out) {
    const int flag = FLAG[0];
    int lane = threadIdx.x & 63;
    int n = blockIdx.x * 4 + (threadIdx.x >> 6);
    int begin = __builtin_amdgcn_readfirstlane(row_ptr[n]);
    int deg   = __builtin_amdgcn_readfirstlane(row_ptr[n + 1]) - begin;
    float c50 = PAR[P_CVEC + 8], c51 = PAR[P_CVEC + 9];
    float ce0 = PAR[P_CVEC + 10], ce1 = PAR[P_CVEC + 11];
    float b5v = PAR[P_SC5], a5s = PAR[P_SC5 + 1];
    float hd = PAR[P_SC5 + 2] * hw5[n];

    float m = -3.4e38f;
    for (int j0 = 0; j0 < deg; j0 += 64) {
        int j = j0 + lane;
        if (j < deg) {
            int2 ce = csr[begin + j];
            uint32 eb = (uint32)ce.y;
            float L = fmaf(hi2f(eb), c51, fmaf(lo2f(eb), c50, fmaf(a5s, hw5[ce.x], hd)));
            L = (L > 0.f) ? L : 0.2f * L;
            m = fmaxf(m, L);
        }
    }
#pragma unroll
    for (int o = 32; o; o >>= 1) m = fmaxf(m, __shfl_xor(m, o, 64));

    float dsum = 0.f, msum = 0.f;
    for (int j0 = 0; j0 < deg; j0 += 64) {
        int j = j0 + lane;
        if (j < deg) {
            int2 ce = csr[begin + j];
            uint32 eb = (uint32)ce.y;
            float hs5 = hw5[ce.x];
            float L = fmaf(hi2f(eb), c51, fmaf(lo2f(eb), c50, fmaf(a5s, hs5, hd)));
            L = (L > 0.f) ? L : 0.2f * L;
            float ex = __expf(L - m);
            dsum += ex;
            msum = fmaf(ex, hs5 + fmaf(hi2f(eb), ce1, lo2f(eb) * ce0), msum);
        }
    }
#pragma unroll
    for (int o = 32; o; o >>= 1) {
        dsum += __shfl_xor(dsum, o, 64);
        msum += __shfl_xor(msum, o, 64);
    }
    if (lane == 0) {
        float r = msum / (dsum + 1e-16f) + b5v;
        if (flag) ((float*)out)[n] = r;
        else      ((u16b*)out)[n] = (u16b)f2bf_bits(r);
    }
}

// ---------------------------------------------------------------------------
extern "C" void kernel_launch(void* const* d_in, const int* in_sizes, int n_in,
                              void* d_out, int out_size, void* d_ws, size_t ws_size,
                              hipStream_t stream) {
    const void* x   = d_in[0];
    const int*  ei  = (const int*)d_in[1];
    const void* ea  = d_in[2];
    const int*  cur = (const int*)d_in[3];
    const void* vge = d_in[4];
    const void* vnd = d_in[5];
    const void* pW  = d_in[6];
    const void* pb  = d_in[7];
    const void* Ws  = d_in[8];
    const void* bs  = d_in[9];
    const void* asr = d_in[10];
    const void* ads = d_in[11];
    const void* aeg = d_in[12];
    const void* Wes = d_in[13];
    const void* W5  = d_in[14];
    const void* b5  = d_in[15];
    const void* as5 = d_in[16];
    const void* ad5 = d_in[17];
    const void* ae5 = d_in[18];
    const void* We5 = d_in[19];
    (void)in_sizes; (void)n_in; (void)out_size;

    const int* e_src = ei;
    const int* e_dst = ei + EE;

    size_t off = 0;
    char* base = (char*)d_ws;
    auto carve = [&](size_t bytes) {
        void* p = base + off;
        off += (bytes + 255) & ~(size_t)255;
        return p;
    };
    int*    FLAG   = (int*)carve(256);
    float*  PAR    = (float*)carve((size_t)P_TOT * 4);
    u16b*   WB     = (u16b*)carve(4 * DD * DD * 2);      // MFMA B fragments
    uint32* H0     = (uint32*)carve((size_t)NV * DD * 2);
    uint32* H1     = (uint32*)carve((size_t)NV * DD * 2);
    float*  SS     = (float*)carve(NV * 4);              // contiguous with SD
    float*  SD     = (float*)carve(NV * 4);
    float*  HW5v   = (float*)carve(NV * 4);
    int*    COUNTS = (int*)carve(65536 * 4);
    int*    ROWPTR = (int*)carve(65536 * 4);
    int*    CURSOR = (int*)carve(NV * 4);
    int*    PART   = (int*)carve(256 * 4);
    int*    BOFF   = (int*)carve(256 * 4);
    int2*   CSR    = (int2*)carve((size_t)EE * 8);
    size_t need = off;

    sniff_kernel<<<1, 256, 0, stream>>>((const unsigned short*)ea, FLAG);

    if (need > ws_size) {
        zero_out_kernel<<<(NV + 255) / 256, 256, 0, stream>>>(
            d_out, FLAG, (float)(ws_size >> 20));
        return;
    }

    prep_kernel<<<5, 256, 0, stream>>>(Wes, aeg, We5, ae5, asr, ads, bs,
                                       W5, b5, as5, ad5, FLAG, PAR);
    prepack_kernel<<<32, 256, 0, stream>>>(Ws, FLAG, WB);
    proj_kernel<<<NV / 4, 256, 0, stream>>>(x, pW, pb, cur, vge, vnd, FLAG, H0);

    hipMemsetAsync(COUNTS, 0, 65536 * 4, stream);
    hist_kernel<<<EE / 256, 256, 0, stream>>>(e_dst, COUNTS);
    scan1_kernel<<<63, 256, 0, stream>>>(COUNTS, ROWPTR, PART);
    scan2_kernel<<<1, 64, 0, stream>>>(PART, BOFF, 63);
    scan3_kernel<<<63, 256, 0, stream>>>(ROWPTR, BOFF, CURSOR);
    scatter_kernel<<<EE / 256, 256, 0, stream>>>(e_src, e_dst, ea, FLAG, CURSOR, CSR);

    for (int l = 0; l < 4; ++l) {
        hipMemsetAsync(SS, 0, (size_t)NV * 8, stream);   // SS + SD contiguous
        // PAR pointer shifted so P_ASRC/P_ADST land on layer l's vectors
        for (int half = 0; half < 2; ++half) {
            gemm_kernel<<<NV / 64, 256, 0, stream>>>(
                H0, WB + (size_t)l * 16384, PAR + l * DD, H1, SS, SD, half * 64);
        }
        agg_kernel<<<NV / 4, 256, 0, stream>>>(
            H1, SS, SD, CSR, ROWPTR, PAR, l, H0);
    }

    hw5_kernel<<<NV / 4, 256, 0, stream>>>(H0, PAR, HW5v);
    final_kernel<<<NV / 4, 256, 0, stream>>>(HW5v, CSR, ROWPTR, PAR, FLAG, d_out);
}

// Round 6
// 504.682 us; speedup vs baseline: 1.6655x; 1.1494x over previous
//
#include <hip/hip_runtime.h>
#include <hip/hip_bf16.h>

// Problem constants (fixed by the reference).
#define BB   128
#define NN   500
#define NV   64000        // BB*NN nodes
#define EE   1048576      // edges
#define DD   128
#define FIN  5
#define VNN  10
#define NBUK 250          // dst>>8 buckets (250*256 = 64000)
#define BCAP 8192         // bucket capacity (expected 4194, >50 sigma margin)

typedef unsigned int   uint32;
typedef unsigned short u16b;
typedef __attribute__((ext_vector_type(8))) short short8;   // 8 bf16 (4 VGPRs)
typedef __attribute__((ext_vector_type(4))) float float4v;  // MFMA C/D

// fp32 param-block layout (element offsets)
#define P_ASRC  0          // 4*128
#define P_ADST  512        // 4*128
#define P_WE    1024       // 4*2*128
#define P_BIAS  2048       // 4*128
#define P_W5    2560       // 128
#define P_CVEC  2688       // 12
#define P_SC5   2700       // b5, as5, ad5
#define P_TOT   2816

static __device__ __forceinline__ float bf2f(__hip_bfloat16 v) { return __bfloat162float(v); }
static __device__ __forceinline__ float lo2f(uint32 u) { return __uint_as_float(u << 16); }
static __device__ __forceinline__ float hi2f(uint32 u) { return __uint_as_float(u & 0xFFFF0000u); }
static __device__ __forceinline__ uint32 f2bf_bits(float f) {
    uint32 u = __float_as_uint(f);
    return (u + 0x7FFFu + ((u >> 16) & 1u)) >> 16;
}
static __device__ __forceinline__ uint32 pack2(float a, float b) {
    return (f2bf_bits(a) & 0xFFFFu) | (f2bf_bits(b) << 16);
}
// flag-dispatched loads (cold paths only): 1 -> fp32 container, 0 -> bf16
static __device__ __forceinline__ float ldf(const void* p, int i, int flag) {
    return flag ? ((const float*)p)[i] : bf2f(((const __hip_bfloat16*)p)[i]);
}

// ---------------------------------------------------------------------------
// dtype sniffer on edge_attr (uniform[0,1))
__global__ void sniff_kernel(const unsigned short* __restrict__ p16, int* __restrict__ FLAG) {
    __shared__ int sHigh, sZero;
    if (threadIdx.x == 0) { sHigh = 0; sZero = 0; }
    __syncthreads();
    unsigned short v = p16[2 * threadIdx.x];
    if (v >= 0x8000u) atomicOr(&sHigh, 1);
    if (v == 0)       atomicAdd(&sZero, 1);
    __syncthreads();
    if (threadIdx.x == 0) FLAG[0] = (sHigh || sZero >= 128) ? 1 : 0;
}

// fallback when workspace too small: zeros + ws_size tag in out[0]
__global__ void zero_out_kernel(void* __restrict__ out, const int* __restrict__ FLAG, float tag) {
    int i = blockIdx.x * blockDim.x + threadIdx.x;
    if (i >= NV) return;
    float v = (i == 0) ? tag : 0.f;
    if (FLAG[0]) ((float*)out)[i] = v;
    else         ((u16b*)out)[i] = (u16b)f2bf_bits(v);
}

// ---------------------------------------------------------------------------
// prep: small fp32 params + attention-edge scalars
__global__ void prep_kernel(const void* __restrict__ Wes, const void* __restrict__ aeg,
                            const void* __restrict__ We5, const void* __restrict__ ae5,
                            const void* __restrict__ asr, const void* __restrict__ ads,
                            const void* __restrict__ bs, const void* __restrict__ W5,
                            const void* __restrict__ b5, const void* __restrict__ as5,
                            const void* __restrict__ ad5, const int* __restrict__ FLAG,
                            float* __restrict__ PAR) {
    const int flag = FLAG[0];
    if (blockIdx.x == 0) {
        for (int i = threadIdx.x; i < 512; i += 256) PAR[P_ASRC + i] = ldf(asr, i, flag);
    } else if (blockIdx.x == 1) {
        for (int i = threadIdx.x; i < 512; i += 256) PAR[P_ADST + i] = ldf(ads, i, flag);
    } else if (blockIdx.x == 2) {
        for (int i = threadIdx.x; i < 1024; i += 256) PAR[P_WE + i] = ldf(Wes, i, flag);
    } else if (blockIdx.x == 3) {
        for (int i = threadIdx.x; i < 512; i += 256) PAR[P_BIAS + i] = ldf(bs, i, flag);
    } else if (blockIdx.x == 4) {
        int tid = threadIdx.x;
        if (tid < 128) {
            PAR[P_W5 + tid] = ldf(W5, tid, flag);
        } else if (tid < 136) {
            int l = (tid - 128) >> 1, r = (tid - 128) & 1;
            float s = 0.f;
            for (int ch = 0; ch < DD; ++ch)
                s += ldf(Wes, l * 256 + r * DD + ch, flag) * ldf(aeg, l * DD + ch, flag);
            PAR[P_CVEC + l * 2 + r] = s;
        } else if (tid == 136) {
            float ae = ldf(ae5, 0, flag);
            float w0 = ldf(We5, 0, flag), w1 = ldf(We5, 1, flag);
            PAR[P_CVEC + 8] = w0 * ae; PAR[P_CVEC + 9] = w1 * ae;
            PAR[P_CVEC + 10] = w0;     PAR[P_CVEC + 11] = w1;
            PAR[P_SC5 + 0] = ldf(b5, 0, flag);
            PAR[P_SC5 + 1] = ldf(as5, 0, flag);
            PAR[P_SC5 + 2] = ldf(ad5, 0, flag);
        }
    }
}

// ---------------------------------------------------------------------------
// prepack W (4 layers, 128x128) into MFMA B-fragment layout (bf16):
// fragment f = l*32 + kblk*8 + nchunk; lane holds B[k=kblk*32+quad*8+j][n=nchunk*16+(lane&15)]
__global__ __launch_bounds__(256) void prepack_kernel(const void* __restrict__ Ws,
                                                      const int* __restrict__ FLAG,
                                                      u16b* __restrict__ WB) {
    const int flag = FLAG[0];
    int t = blockIdx.x * 256 + threadIdx.x;   // 8192 threads
    int lane = t & 63;
    int frag = t >> 6;                        // l*32 + kblk*8 + nchunk
    int nchunk = frag & 7, kblk = (frag >> 3) & 3, l = frag >> 5;
    int n = nchunk * 16 + (lane & 15);
    int kbase = kblk * 32 + (lane >> 4) * 8;
#pragma unroll
    for (int j = 0; j < 8; ++j) {
        int idx = l * 16384 + (kbase + j) * 128 + n;
        u16b bits = flag ? (u16b)f2bf_bits(((const float*)Ws)[idx])
                         : ((const u16b*)Ws)[idx];
        WB[(size_t)t * 8 + j] = bits;
    }
}

// ---------------------------------------------------------------------------
// input projection: h0 = lrelu(x@pW + pb, .01) + vge[b] + vnd[b, curr[b]]
__global__ __launch_bounds__(256) void proj_kernel(
        const void* __restrict__ x, const void* __restrict__ pW,
        const void* __restrict__ pb, const int* __restrict__ curr,
        const void* __restrict__ vge, const void* __restrict__ vnd,
        const int* __restrict__ FLAG, uint32* __restrict__ H) {
    const int flag = FLAG[0];
    const int n = blockIdx.x * 4 + (threadIdx.x >> 6);
    const int lane = threadIdx.x & 63;
    const int b = n / NN;
    int cv = curr[b]; if ((unsigned)cv >= VNN) cv = 0;
    float xv[FIN];
#pragma unroll
    for (int k = 0; k < FIN; ++k) xv[k] = ldf(x, n * FIN + k, flag);
    const int ch = lane * 2;
    float s0 = ldf(pb, ch, flag), s1 = ldf(pb, ch + 1, flag);
#pragma unroll
    for (int k = 0; k < FIN; ++k) {
        s0 = fmaf(xv[k], ldf(pW, k * DD + ch, flag), s0);
        s1 = fmaf(xv[k], ldf(pW, k * DD + ch + 1, flag), s1);
    }
    s0 = (s0 > 0.f) ? s0 : 0.01f * s0;
    s1 = (s1 > 0.f) ? s1 : 0.01f * s1;
    s0 += ldf(vge, b * DD + ch, flag) + ldf(vnd, (b * VNN + cv) * DD + ch, flag);
    s1 += ldf(vge, b * DD + ch + 1, flag) + ldf(vnd, (b * VNN + cv) * DD + ch + 1, flag);
    H[(size_t)n * 64 + lane] = pack2(s0, s1);
}

// ---------------------------------------------------------------------------
// CSR build, 2-level bucket sort.
// init: bucket cursors + COUNTS tail zero
__global__ void init_kernel(int* __restrict__ gcur, int* __restrict__ counts) {
    int t = blockIdx.x * 256 + threadIdx.x;
    if (t < NBUK) gcur[t] = t * BCAP;
    if (t < 512) counts[NV + t] = 0;
}

// pass 1: bucketize by dst>>8. Per-block LDS histogram -> one global atomic per
// (block,bucket) to reserve a contiguous range -> cursor-localized writes.
__global__ __launch_bounds__(256) void bucketize_kernel(
        const int* __restrict__ src, const int* __restrict__ dst,
        const void* __restrict__ eaP, const int* __restrict__ FLAG,
        int* __restrict__ gcur, uint32* __restrict__ bukx, uint32* __restrict__ buky) {
    __shared__ int cnt[256];
    __shared__ int cur[256];
    const int flag = FLAG[0];
    const int t = threadIdx.x;
    const int e0 = blockIdx.x * 4096;
    cnt[t] = 0;
    __syncthreads();
    int d[16];
#pragma unroll
    for (int i = 0; i < 16; ++i) {
        d[i] = dst[e0 + i * 256 + t];
        if ((unsigned)d[i] >= NV) d[i] = -1;
        if (d[i] >= 0) atomicAdd(&cnt[d[i] >> 8], 1);
    }
    __syncthreads();
    if (t < NBUK) {
        int c = cnt[t];
        cur[t] = c ? atomicAdd(&gcur[t], c) : 0;
    }
    __syncthreads();
#pragma unroll
    for (int i = 0; i < 16; ++i) {
        if (d[i] < 0) continue;
        int e = e0 + i * 256 + t;
        int b = d[i] >> 8;
        int s = src[e];
        if ((unsigned)s >= NV) s = 0;
        uint32 eb;
        if (flag) { float2 v = ((const float2*)eaP)[e]; eb = pack2(v.x, v.y); }
        else      eb = ((const uint32*)eaP)[e];
        int p = atomicAdd(&cur[b], 1);
        if (p < (b + 1) * BCAP) {
            bukx[p] = (uint32)((s & 0xFFFF) | ((d[i] & 255) << 16));
            buky[p] = eb;
        }
    }
}

// per-bucket dst histogram -> COUNTS (sequential stores; replaces global hist)
__global__ __launch_bounds__(256) void bcount_kernel(
        const uint32* __restrict__ bukx, const int* __restrict__ gcur,
        int* __restrict__ counts) {
    __shared__ int c[256];
    const int b = blockIdx.x, t = threadIdx.x;
    c[t] = 0;
    __syncthreads();
    const int base = b * BCAP;
    int cnt = gcur[b] - base;
    if (cnt > BCAP) cnt = BCAP;
    for (int i = t; i < cnt; i += 256)
        atomicAdd(&c[(bukx[base + i] >> 16) & 255], 1);
    __syncthreads();
    counts[b * 256 + t] = c[t];
}

__global__ __launch_bounds__(256) void scan1_kernel(const int* __restrict__ counts,
                                                    int* __restrict__ row_ptr,
                                                    int* __restrict__ partials) {
    __shared__ int sdata[256];
    int tid = threadIdx.x;
    int4 v = ((const int4*)counts)[blockIdx.x * 256 + tid];
    int sum = v.x + v.y + v.z + v.w;
    sdata[tid] = sum;
    __syncthreads();
    int acc = sum;
    for (int off = 1; off < 256; off <<= 1) {
        int t = (tid >= off) ? sdata[tid - off] : 0;
        __syncthreads();
        acc += t;
        sdata[tid] = acc;
        __syncthreads();
    }
    int excl = acc - sum;
    int base = blockIdx.x * 1024 + tid * 4;
    int run = excl;
    if (base + 0 <= NV) row_ptr[base + 0] = run; run += v.x;
    if (base + 1 <= NV) row_ptr[base + 1] = run; run += v.y;
    if (base + 2 <= NV) row_ptr[base + 2] = run; run += v.z;
    if (base + 3 <= NV) row_ptr[base + 3] = run;
    if (tid == 255) partials[blockIdx.x] = acc;
}

__global__ __launch_bounds__(64) void scan2_kernel(const int* __restrict__ partials,
                                                   int* __restrict__ boff, int nb) {
    int lane = threadIdx.x;
    int v = (lane < nb) ? partials[lane] : 0;
    int orig = v;
#pragma unroll
    for (int off = 1; off < 64; off <<= 1) {
        int t = __shfl_up(v, off, 64);
        if (lane >= off) v += t;
    }
    boff[lane] = v - orig;
}

__global__ __launch_bounds__(256) void scan3_kernel(int* __restrict__ row_ptr,
                                                    const int* __restrict__ boff) {
    int add = boff[blockIdx.x];
    int base = blockIdx.x * 1024 + threadIdx.x * 4;
#pragma unroll
    for (int j = 0; j < 4; ++j) {
        int i = base + j;
        if (i <= NV) row_ptr[i] += add;
    }
}

// pass 2: within-bucket scatter to final CSR (SoA). Writes confined to the
// bucket's ~34KB row_ptr window -> L2-coalesced, write-amp ~1.
__global__ __launch_bounds__(256) void bscatter_kernel(
        const uint32* __restrict__ bukx, const uint32* __restrict__ buky,
        const int* __restrict__ gcur, const int* __restrict__ row_ptr,
        int* __restrict__ csr_src, uint32* __restrict__ csr_ea) {
    __shared__ int cur[256];
    const int b = blockIdx.x, t = threadIdx.x;
    cur[t] = row_ptr[b * 256 + t];
    __syncthreads();
    const int base = b * BCAP;
    int cnt = gcur[b] - base;
    if (cnt > BCAP) cnt = BCAP;
    for (int i = t; i < cnt; i += 256) {
        uint32 x = bukx[base + i];
        uint32 y = buky[base + i];
        int p = atomicAdd(&cur[(x >> 16) & 255], 1);
        csr_src[p] = (int)(x & 0xFFFFu);
        csr_ea[p] = y;
    }
}

// ---------------------------------------------------------------------------
// MFMA GEMM, full 128 cols per block: HW = H @ W + fused attention dots.
// Block = 64 nodes; wave w handles nodes [n0+16w,+16) x all 128 cols (8 tiles).
__global__ __launch_bounds__(256) void gemm_kernel(
        const uint32* __restrict__ Hu, const u16b* __restrict__ WBl,
        const float* __restrict__ PARl, uint32* __restrict__ HWu,
        float* __restrict__ ssrc, float* __restrict__ sdst) {
    __shared__ float hs[64 * 129];
    __shared__ float pp[512];
    const int tid = threadIdx.x;
    const int lane = tid & 63;
    const int wave = tid >> 6;
    const int quad = lane >> 4;
    const int n0 = blockIdx.x * 64;
    const int m = n0 + wave * 16 + (lane & 15);

    const u16b* hrow = (const u16b*)Hu + (size_t)m * 128;
    short8 a0 = *(const short8*)(hrow + 0  + quad * 8);
    short8 a1 = *(const short8*)(hrow + 32 + quad * 8);
    short8 a2 = *(const short8*)(hrow + 64 + quad * 8);
    short8 a3 = *(const short8*)(hrow + 96 + quad * 8);

#pragma unroll
    for (int nt = 0; nt < 8; ++nt) {
        const u16b* bbase = WBl + ((size_t)nt * 512 + lane * 8);
        short8 b0 = *(const short8*)(bbase + 0 * 4096);
        short8 b1 = *(const short8*)(bbase + 1 * 4096);
        short8 b2 = *(const short8*)(bbase + 2 * 4096);
        short8 b3 = *(const short8*)(bbase + 3 * 4096);
        float4v acc = {0.f, 0.f, 0.f, 0.f};
        acc = __builtin_amdgcn_mfma_f32_16x16x32_bf16(a0, b0, acc, 0, 0, 0);
        acc = __builtin_amdgcn_mfma_f32_16x16x32_bf16(a1, b1, acc, 0, 0, 0);
        acc = __builtin_amdgcn_mfma_f32_16x16x32_bf16(a2, b2, acc, 0, 0, 0);
        acc = __builtin_amdgcn_mfma_f32_16x16x32_bf16(a3, b3, acc, 0, 0, 0);
#pragma unroll
        for (int r = 0; r < 4; ++r)
            hs[(wave * 16 + quad * 4 + r) * 129 + nt * 16 + (lane & 15)] = acc[r];
    }
    __syncthreads();

    // attention dots: thread t -> node (t&63), col group (t>>6)*32
    {
        const int mn = tid & 63, cg = tid >> 6;
        const float* Asr = PARl + P_ASRC;
        const float* Ads = PARl + P_ADST;
        const float* row = hs + mn * 129 + cg * 32;
        float ps = 0.f, pd = 0.f;
#pragma unroll
        for (int j = 0; j < 32; ++j) {
            float v = row[j];
            ps = fmaf(v, Asr[cg * 32 + j], ps);
            pd = fmaf(v, Ads[cg * 32 + j], pd);
        }
        pp[tid] = ps; pp[256 + tid] = pd;
    }
    __syncthreads();
    if (tid < 64) {
        ssrc[n0 + tid] = pp[tid] + pp[64 + tid] + pp[128 + tid] + pp[192 + tid];
        sdst[n0 + tid] = pp[256 + tid] + pp[320 + tid] + pp[384 + tid] + pp[448 + tid];
    }

    // bf16 pack + coalesced store
#pragma unroll
    for (int i = 0; i < 4; ++i) {
        int flat = i * 2048 + tid * 8;
        int n = flat >> 7, c = flat & 127;
        const float* p = hs + n * 129 + c;
        uint4 v;
        v.x = pack2(p[0], p[1]); v.y = pack2(p[2], p[3]);
        v.z = pack2(p[4], p[5]); v.w = pack2(p[6], p[7]);
        *(uint4*)(HWu + (size_t)(n0 + n) * 64 + c / 2) = v;
    }
}

// ---------------------------------------------------------------------------
// Hidden-layer attention + aggregation. One wave per dst node.
__global__ __launch_bounds__(256) void agg_kernel(
        const uint32* __restrict__ HWu, const float* __restrict__ ssrc,
        const float* __restrict__ sdst, const int* __restrict__ csr_src,
        const uint32* __restrict__ csr_ea, const int* __restrict__ row_ptr,
        const float* __restrict__ PAR, int layer, uint32* __restrict__ HoutU) {
    const int lane = threadIdx.x & 63;
    const int n = blockIdx.x * 4 + (threadIdx.x >> 6);
    const int begin = __builtin_amdgcn_readfirstlane(row_ptr[n]);
    const int deg   = __builtin_amdgcn_readfirstlane(row_ptr[n + 1]) - begin;
    const float c0 = PAR[P_CVEC + 2 * layer], c1 = PAR[P_CVEC + 2 * layer + 1];
    const float sd = sdst[n];

    float m = -3.4e38f;
    for (int j0 = 0; j0 < deg; j0 += 64) {
        int j = j0 + lane;
        if (j < deg) {
            int s = csr_src[begin + j];
            uint32 eb = csr_ea[begin + j];
            float L = fmaf(hi2f(eb), c1, fmaf(lo2f(eb), c0, ssrc[s] + sd));
            L = (L > 0.f) ? L : 0.2f * L;
            m = fmaxf(m, L);
        }
    }
#pragma unroll
    for (int o = 32; o; o >>= 1) m = fmaxf(m, __shfl_xor(m, o, 64));

    const int ch = lane * 2;
    const float* WEl = PAR + P_WE + layer * 256;
    const float w0x = WEl[ch],      w0y = WEl[ch + 1];
    const float w1x = WEl[DD + ch], w1y = WEl[DD + ch + 1];

    float dsum = 0.f, acc0 = 0.f, acc1 = 0.f;
    int jj = 0;
    for (; jj + 8 <= deg; jj += 8) {
        int sv[8]; uint32 ev[8]; float g[8]; uint32 hv[8];
#pragma unroll
        for (int q = 0; q < 8; ++q) sv[q] = csr_src[begin + jj + q];
#pragma unroll
        for (int q = 0; q < 8; ++q) ev[q] = csr_ea[begin + jj + q];
#pragma unroll
        for (int q = 0; q < 8; ++q) g[q] = ssrc[sv[q]];
#pragma unroll
        for (int q = 0; q < 8; ++q) hv[q] = HWu[(size_t)sv[q] * 64 + lane];
#pragma unroll
        for (int q = 0; q < 8; ++q) {
            uint32 eb = ev[q];
            float L = fmaf(hi2f(eb), c1, fmaf(lo2f(eb), c0, g[q] + sd));
            L = (L > 0.f) ? L : 0.2f * L;
            float ex = __expf(L - m);
            dsum += ex;
            acc0 = fmaf(ex, lo2f(hv[q]) + fmaf(hi2f(eb), w1x, lo2f(eb) * w0x), acc0);
            acc1 = fmaf(ex, hi2f(hv[q]) + fmaf(hi2f(eb), w1y, lo2f(eb) * w0y), acc1);
        }
    }
    for (; jj < deg; ++jj) {
        int s = csr_src[begin + jj];
        uint32 eb = csr_ea[begin + jj];
        float L = fmaf(hi2f(eb), c1, fmaf(lo2f(eb), c0, ssrc[s] + sd));
        L = (L > 0.f) ? L : 0.2f * L;
        float ex = __expf(L - m);
        dsum += ex;
        uint32 hb = HWu[(size_t)s * 64 + lane];
        acc0 = fmaf(ex, lo2f(hb) + fmaf(hi2f(eb), w1x, lo2f(eb) * w0x), acc0);
        acc1 = fmaf(ex, hi2f(hb) + fmaf(hi2f(eb), w1y, lo2f(eb) * w0y), acc1);
    }
    const float inv = 1.f / (dsum + 1e-16f);
    const float* Bl = PAR + P_BIAS + layer * DD;
    float o0 = fmaf(acc0, inv, Bl[ch]);
    float o1 = fmaf(acc1, inv, Bl[ch + 1]);
    o0 = (o0 > 0.f) ? o0 : 0.01f * o0;
    o1 = (o1 > 0.f) ? o1 : 0.01f * o1;
    HoutU[(size_t)n * 64 + lane] = pack2(o0, o1);
}

// ---------------------------------------------------------------------------
__global__ __launch_bounds__(256) void hw5_kernel(const uint32* __restrict__ Hu,
                                                  const float* __restrict__ PAR,
                                                  float* __restrict__ hw5) {
    int lane = threadIdx.x & 63;
    int n = blockIdx.x * 4 + (threadIdx.x >> 6);
    uint32 hb = Hu[(size_t)n * 64 + lane];
    float p = lo2f(hb) * PAR[P_W5 + 2 * lane] + hi2f(hb) * PAR[P_W5 + 2 * lane + 1];
#pragma unroll
    for (int o = 32; o; o >>= 1) p += __shfl_xor(p, o, 64);
    if (lane == 0) hw5[n] = p;
}

__global__ __launch_bounds__(256) void final_kernel(
        const float* __restrict__ hw5, const int* __restrict__ csr_src,
        const uint32* __restrict__ csr_ea, const int* __restrict__ row_ptr,
        const float* __restrict__ PAR, const int* __restrict__ FLAG,
        void* __restrict__ out) {
    const int flag = FLAG[0];
    int lane = threadIdx.x & 63;
    int n = blockIdx.x * 4 + (threadIdx.x >> 6);
    int begin = __builtin_amdgcn_readfirstlane(row_ptr[n]);
    int deg   = __builtin_amdgcn_readfirstlane(row_ptr[n + 1]) - begin;
    float c50 = PAR[P_CVEC + 8], c51 = PAR[P_CVEC + 9];
    float ce0 = PAR[P_CVEC + 10], ce1 = PAR[P_CVEC + 11];
    float b5v = PAR[P_SC5], a5s = PAR[P_SC5 + 1];
    float hd = PAR[P_SC5 + 2] * hw5[n];

    float m = -3.4e38f;
    for (int j0 = 0; j0 < deg; j0 += 64) {
        int j = j0 + lane;
        if (j < deg) {
            int s = csr_src[begin + j];
            uint32 eb = csr_ea[begin + j];
            float L = fmaf(hi2f(eb), c51, fmaf(lo2f(eb), c50, fmaf(a5s, hw5[s], hd)));
            L = (L > 0.f) ? L : 0.2f * L;
            m = fmaxf(m, L);
        }
    }
#pragma unroll
    for (int o = 32; o; o >>= 1) m = fmaxf(m, __shfl_xor(m, o, 64));

    float dsum = 0.f, msum = 0.f;
    for (int j0 = 0; j0 < deg; j0 += 64) {
        int j = j0 + lane;
        if (j < deg) {
            int s = csr_src[begin + j];
            uint32 eb = csr_ea[begin + j];
            float hs5 = hw5[s];
            float L = fmaf(hi2f(eb), c51, fmaf(lo2f(eb), c50, fmaf(a5s, hs5, hd)));
            L = (L > 0.f) ? L : 0.2f * L;
            float ex = __expf(L - m);
            dsum += ex;
            msum = fmaf(ex, hs5 + fmaf(hi2f(eb), ce1, lo2f(eb) * ce0), msum);
        }
    }
#pragma unroll
    for (int o = 32; o; o >>= 1) {
        dsum += __shfl_xor(dsum, o, 64);
        msum += __shfl_xor(msum, o, 64);
    }
    if (lane == 0) {
        float r = msum / (dsum + 1e-16f) + b5v;
        if (flag) ((float*)out)[n] = r;
        else      ((u16b*)out)[n] = (u16b)f2bf_bits(r);
    }
}

// ---------------------------------------------------------------------------
extern "C" void kernel_launch(void* const* d_in, const int* in_sizes, int n_in,
                              void* d_out, int out_size, void* d_ws, size_t ws_size,
                              hipStream_t stream) {
    const void* x   = d_in[0];
    const int*  ei  = (const int*)d_in[1];
    const void* ea  = d_in[2];
    const int*  cur = (const int*)d_in[3];
    const void* vge = d_in[4];
    const void* vnd = d_in[5];
    const void* pW  = d_in[6];
    const void* pb  = d_in[7];
    const void* Ws  = d_in[8];
    const void* bs  = d_in[9];
    const void* asr = d_in[10];
    const void* ads = d_in[11];
    const void* aeg = d_in[12];
    const void* Wes = d_in[13];
    const void* W5  = d_in[14];
    const void* b5  = d_in[15];
    const void* as5 = d_in[16];
    const void* ad5 = d_in[17];
    const void* ae5 = d_in[18];
    const void* We5 = d_in[19];
    (void)in_sizes; (void)n_in; (void)out_size;

    const int* e_src = ei;
    const int* e_dst = ei + EE;

    size_t off = 0;
    char* base = (char*)d_ws;
    auto carve = [&](size_t bytes) {
        void* p = base + off;
        off += (bytes + 255) & ~(size_t)255;
        return p;
    };
    int*    FLAG   = (int*)carve(256);
    float*  PAR    = (float*)carve((size_t)P_TOT * 4);
    u16b*   WB     = (u16b*)carve(4 * DD * DD * 2);      // MFMA B fragments
    uint32* H0     = (uint32*)carve((size_t)NV * DD * 2);
    uint32* H1     = (uint32*)carve((size_t)NV * DD * 2); // also bucket storage
    float*  SS     = (float*)carve(NV * 4);
    float*  SD     = (float*)carve(NV * 4);
    float*  HW5v   = (float*)carve(NV * 4);
    int*    COUNTS = (int*)carve(65536 * 4);
    int*    ROWPTR = (int*)carve(65536 * 4);
    int*    GCUR   = (int*)carve(256 * 4);
    int*    PART   = (int*)carve(256 * 4);
    int*    BOFF   = (int*)carve(256 * 4);
    int*    CSRS   = (int*)carve((size_t)EE * 4);
    uint32* CSREA  = (uint32*)carve((size_t)EE * 4);
    size_t need = off;

    // bucket storage aliases H1 (used strictly before the layer loop)
    uint32* BUKX = H1;                       // NBUK*BCAP uints = 8.19 MB
    uint32* BUKY = H1 + (size_t)NBUK * BCAP; // 8.19 MB  (total = H1 size)

    sniff_kernel<<<1, 256, 0, stream>>>((const unsigned short*)ea, FLAG);

    if (need > ws_size) {
        zero_out_kernel<<<(NV + 255) / 256, 256, 0, stream>>>(
            d_out, FLAG, (float)(ws_size >> 20));
        return;
    }

    prep_kernel<<<5, 256, 0, stream>>>(Wes, aeg, We5, ae5, asr, ads, bs,
                                       W5, b5, as5, ad5, FLAG, PAR);
    prepack_kernel<<<32, 256, 0, stream>>>(Ws, FLAG, WB);
    proj_kernel<<<NV / 4, 256, 0, stream>>>(x, pW, pb, cur, vge, vnd, FLAG, H0);

    init_kernel<<<2, 256, 0, stream>>>(GCUR, COUNTS);
    bucketize_kernel<<<EE / 4096, 256, 0, stream>>>(e_src, e_dst, ea, FLAG,
                                                    GCUR, BUKX, BUKY);
    bcount_kernel<<<NBUK, 256, 0, stream>>>(BUKX, GCUR, COUNTS);
    scan1_kernel<<<63, 256, 0, stream>>>(COUNTS, ROWPTR, PART);
    scan2_kernel<<<1, 64, 0, stream>>>(PART, BOFF, 63);
    scan3_kernel<<<63, 256, 0, stream>>>(ROWPTR, BOFF);
    bscatter_kernel<<<NBUK, 256, 0, stream>>>(BUKX, BUKY, GCUR, ROWPTR,
                                              CSRS, CSREA);

    for (int l = 0; l < 4; ++l) {
        gemm_kernel<<<NV / 64, 256, 0, stream>>>(
            H0, WB + (size_t)l * 16384, PAR + l * DD, H1, SS, SD);
        agg_kernel<<<NV / 4, 256, 0, stream>>>(
            H1, SS, SD, CSRS, CSREA, ROWPTR, PAR, l, H0);
    }

    hw5_kernel<<<NV / 4, 256, 0, stream>>>(H0, PAR, HW5v);
    final_kernel<<<NV / 4, 256, 0, stream>>>(HW5v, CSRS, CSREA, ROWPTR, PAR,
                                             FLAG, d_out);
}

// Round 7
// 464.553 us; speedup vs baseline: 1.8094x; 1.0864x over previous
//
#include <hip/hip_runtime.h>
#include <hip/hip_bf16.h>

// Problem constants (fixed by the reference).
#define BB   128
#define NN   500
#define NV   64000        // BB*NN nodes
#define EE   1048576      // edges
#define DD   128
#define FIN  5
#define VNN  10
#define NBUK 250          // dst>>8 buckets (250*256 = 64000)
#define BCAP 8192         // bucket capacity (expected 4194, >50 sigma margin)

typedef unsigned int   uint32;
typedef unsigned short u16b;
typedef __attribute__((ext_vector_type(8))) short short8;   // 8 bf16 (4 VGPRs)
typedef __attribute__((ext_vector_type(4))) float float4v;  // MFMA C/D

// fp32 param-block layout (element offsets)
#define P_ASRC  0          // 4*128
#define P_ADST  512        // 4*128
#define P_WE    1024       // 4*2*128
#define P_BIAS  2048       // 4*128
#define P_W5    2560       // 128
#define P_CVEC  2688       // 12
#define P_SC5   2700       // b5, as5, ad5
#define P_TOT   2816

static __device__ __forceinline__ float bf2f(__hip_bfloat16 v) { return __bfloat162float(v); }
static __device__ __forceinline__ float lo2f(uint32 u) { return __uint_as_float(u << 16); }
static __device__ __forceinline__ float hi2f(uint32 u) { return __uint_as_float(u & 0xFFFF0000u); }
static __device__ __forceinline__ uint32 f2bf_bits(float f) {
    uint32 u = __float_as_uint(f);
    return (u + 0x7FFFu + ((u >> 16) & 1u)) >> 16;
}
static __device__ __forceinline__ uint32 pack2(float a, float b) {
    return (f2bf_bits(a) & 0xFFFFu) | (f2bf_bits(b) << 16);
}
// flag-dispatched loads (cold paths only): 1 -> fp32 container, 0 -> bf16
static __device__ __forceinline__ float ldf(const void* p, int i, int flag) {
    return flag ? ((const float*)p)[i] : bf2f(((const __hip_bfloat16*)p)[i]);
}

// ---------------------------------------------------------------------------
// dtype sniffer on edge_attr (uniform[0,1))
__global__ void sniff_kernel(const unsigned short* __restrict__ p16, int* __restrict__ FLAG) {
    __shared__ int sHigh, sZero;
    if (threadIdx.x == 0) { sHigh = 0; sZero = 0; }
    __syncthreads();
    unsigned short v = p16[2 * threadIdx.x];
    if (v >= 0x8000u) atomicOr(&sHigh, 1);
    if (v == 0)       atomicAdd(&sZero, 1);
    __syncthreads();
    if (threadIdx.x == 0) FLAG[0] = (sHigh || sZero >= 128) ? 1 : 0;
}

// fallback when workspace too small: zeros + ws_size tag in out[0]
__global__ void zero_out_kernel(void* __restrict__ out, const int* __restrict__ FLAG, float tag) {
    int i = blockIdx.x * blockDim.x + threadIdx.x;
    if (i >= NV) return;
    float v = (i == 0) ? tag : 0.f;
    if (FLAG[0]) ((float*)out)[i] = v;
    else         ((u16b*)out)[i] = (u16b)f2bf_bits(v);
}

// ---------------------------------------------------------------------------
// prep: small fp32 params + attention-edge scalars
__global__ void prep_kernel(const void* __restrict__ Wes, const void* __restrict__ aeg,
                            const void* __restrict__ We5, const void* __restrict__ ae5,
                            const void* __restrict__ asr, const void* __restrict__ ads,
                            const void* __restrict__ bs, const void* __restrict__ W5,
                            const void* __restrict__ b5, const void* __restrict__ as5,
                            const void* __restrict__ ad5, const int* __restrict__ FLAG,
                            float* __restrict__ PAR) {
    const int flag = FLAG[0];
    if (blockIdx.x == 0) {
        for (int i = threadIdx.x; i < 512; i += 256) PAR[P_ASRC + i] = ldf(asr, i, flag);
    } else if (blockIdx.x == 1) {
        for (int i = threadIdx.x; i < 512; i += 256) PAR[P_ADST + i] = ldf(ads, i, flag);
    } else if (blockIdx.x == 2) {
        for (int i = threadIdx.x; i < 1024; i += 256) PAR[P_WE + i] = ldf(Wes, i, flag);
    } else if (blockIdx.x == 3) {
        for (int i = threadIdx.x; i < 512; i += 256) PAR[P_BIAS + i] = ldf(bs, i, flag);
    } else if (blockIdx.x == 4) {
        int tid = threadIdx.x;
        if (tid < 128) {
            PAR[P_W5 + tid] = ldf(W5, tid, flag);
        } else if (tid < 136) {
            int l = (tid - 128) >> 1, r = (tid - 128) & 1;
            float s = 0.f;
            for (int ch = 0; ch < DD; ++ch)
                s += ldf(Wes, l * 256 + r * DD + ch, flag) * ldf(aeg, l * DD + ch, flag);
            PAR[P_CVEC + l * 2 + r] = s;
        } else if (tid == 136) {
            float ae = ldf(ae5, 0, flag);
            float w0 = ldf(We5, 0, flag), w1 = ldf(We5, 1, flag);
            PAR[P_CVEC + 8] = w0 * ae; PAR[P_CVEC + 9] = w1 * ae;
            PAR[P_CVEC + 10] = w0;     PAR[P_CVEC + 11] = w1;
            PAR[P_SC5 + 0] = ldf(b5, 0, flag);
            PAR[P_SC5 + 1] = ldf(as5, 0, flag);
            PAR[P_SC5 + 2] = ldf(ad5, 0, flag);
        }
    }
}

// ---------------------------------------------------------------------------
// prepack W (4 layers, 128x128) into MFMA B-fragment layout (bf16):
// fragment f = l*32 + kblk*8 + nchunk; lane holds B[k=kblk*32+quad*8+j][n=nchunk*16+(lane&15)]
__global__ __launch_bounds__(256) void prepack_kernel(const void* __restrict__ Ws,
                                                      const int* __restrict__ FLAG,
                                                      u16b* __restrict__ WB) {
    const int flag = FLAG[0];
    int t = blockIdx.x * 256 + threadIdx.x;   // 8192 threads
    int lane = t & 63;
    int frag = t >> 6;                        // l*32 + kblk*8 + nchunk
    int nchunk = frag & 7, kblk = (frag >> 3) & 3, l = frag >> 5;
    int n = nchunk * 16 + (lane & 15);
    int kbase = kblk * 32 + (lane >> 4) * 8;
#pragma unroll
    for (int j = 0; j < 8; ++j) {
        int idx = l * 16384 + (kbase + j) * 128 + n;
        u16b bits = flag ? (u16b)f2bf_bits(((const float*)Ws)[idx])
                         : ((const u16b*)Ws)[idx];
        WB[(size_t)t * 8 + j] = bits;
    }
}

// ---------------------------------------------------------------------------
// input projection: h0 = lrelu(x@pW + pb, .01) + vge[b] + vnd[b, curr[b]]
__global__ __launch_bounds__(256) void proj_kernel(
        const void* __restrict__ x, const void* __restrict__ pW,
        const void* __restrict__ pb, const int* __restrict__ curr,
        const void* __restrict__ vge, const void* __restrict__ vnd,
        const int* __restrict__ FLAG, uint32* __restrict__ H) {
    const int flag = FLAG[0];
    const int n = blockIdx.x * 4 + (threadIdx.x >> 6);
    const int lane = threadIdx.x & 63;
    const int b = n / NN;
    int cv = curr[b]; if ((unsigned)cv >= VNN) cv = 0;
    float xv[FIN];
#pragma unroll
    for (int k = 0; k < FIN; ++k) xv[k] = ldf(x, n * FIN + k, flag);
    const int ch = lane * 2;
    float s0 = ldf(pb, ch, flag), s1 = ldf(pb, ch + 1, flag);
#pragma unroll
    for (int k = 0; k < FIN; ++k) {
        s0 = fmaf(xv[k], ldf(pW, k * DD + ch, flag), s0);
        s1 = fmaf(xv[k], ldf(pW, k * DD + ch + 1, flag), s1);
    }
    s0 = (s0 > 0.f) ? s0 : 0.01f * s0;
    s1 = (s1 > 0.f) ? s1 : 0.01f * s1;
    s0 += ldf(vge, b * DD + ch, flag) + ldf(vnd, (b * VNN + cv) * DD + ch, flag);
    s1 += ldf(vge, b * DD + ch + 1, flag) + ldf(vnd, (b * VNN + cv) * DD + ch + 1, flag);
    H[(size_t)n * 64 + lane] = pack2(s0, s1);
}

// ---------------------------------------------------------------------------
// CSR build, 2-level bucket sort.
__global__ void init_kernel(int* __restrict__ gcur, int* __restrict__ counts) {
    int t = blockIdx.x * 256 + threadIdx.x;
    if (t < NBUK) gcur[t] = t * BCAP;
    if (t < 512) counts[NV + t] = 0;
}

__global__ __launch_bounds__(256) void bucketize_kernel(
        const int* __restrict__ src, const int* __restrict__ dst,
        const void* __restrict__ eaP, const int* __restrict__ FLAG,
        int* __restrict__ gcur, uint32* __restrict__ bukx, uint32* __restrict__ buky) {
    __shared__ int cnt[256];
    __shared__ int cur[256];
    const int flag = FLAG[0];
    const int t = threadIdx.x;
    const int e0 = blockIdx.x * 4096;
    cnt[t] = 0;
    __syncthreads();
    int d[16];
#pragma unroll
    for (int i = 0; i < 16; ++i) {
        d[i] = dst[e0 + i * 256 + t];
        if ((unsigned)d[i] >= NV) d[i] = -1;
        if (d[i] >= 0) atomicAdd(&cnt[d[i] >> 8], 1);
    }
    __syncthreads();
    if (t < NBUK) {
        int c = cnt[t];
        cur[t] = c ? atomicAdd(&gcur[t], c) : 0;
    }
    __syncthreads();
#pragma unroll
    for (int i = 0; i < 16; ++i) {
        if (d[i] < 0) continue;
        int e = e0 + i * 256 + t;
        int b = d[i] >> 8;
        int s = src[e];
        if ((unsigned)s >= NV) s = 0;
        uint32 eb;
        if (flag) { float2 v = ((const float2*)eaP)[e]; eb = pack2(v.x, v.y); }
        else      eb = ((const uint32*)eaP)[e];
        int p = atomicAdd(&cur[b], 1);
        if (p < (b + 1) * BCAP) {
            bukx[p] = (uint32)((s & 0xFFFF) | ((d[i] & 255) << 16));
            buky[p] = eb;
        }
    }
}

__global__ __launch_bounds__(256) void bcount_kernel(
        const uint32* __restrict__ bukx, const int* __restrict__ gcur,
        int* __restrict__ counts) {
    __shared__ int c[256];
    const int b = blockIdx.x, t = threadIdx.x;
    c[t] = 0;
    __syncthreads();
    const int base = b * BCAP;
    int cnt = gcur[b] - base;
    if (cnt > BCAP) cnt = BCAP;
    for (int i = t; i < cnt; i += 256)
        atomicAdd(&c[(bukx[base + i] >> 16) & 255], 1);
    __syncthreads();
    counts[b * 256 + t] = c[t];
}

__global__ __launch_bounds__(256) void scan1_kernel(const int* __restrict__ counts,
                                                    int* __restrict__ row_ptr,
                                                    int* __restrict__ partials) {
    __shared__ int sdata[256];
    int tid = threadIdx.x;
    int4 v = ((const int4*)counts)[blockIdx.x * 256 + tid];
    int sum = v.x + v.y + v.z + v.w;
    sdata[tid] = sum;
    __syncthreads();
    int acc = sum;
    for (int off = 1; off < 256; off <<= 1) {
        int t = (tid >= off) ? sdata[tid - off] : 0;
        __syncthreads();
        acc += t;
        sdata[tid] = acc;
        __syncthreads();
    }
    int excl = acc - sum;
    int base = blockIdx.x * 1024 + tid * 4;
    int run = excl;
    if (base + 0 <= NV) row_ptr[base + 0] = run; run += v.x;
    if (base + 1 <= NV) row_ptr[base + 1] = run; run += v.y;
    if (base + 2 <= NV) row_ptr[base + 2] = run; run += v.z;
    if (base + 3 <= NV) row_ptr[base + 3] = run;
    if (tid == 255) partials[blockIdx.x] = acc;
}

__global__ __launch_bounds__(64) void scan2_kernel(const int* __restrict__ partials,
                                                   int* __restrict__ boff, int nb) {
    int lane = threadIdx.x;
    int v = (lane < nb) ? partials[lane] : 0;
    int orig = v;
#pragma unroll
    for (int off = 1; off < 64; off <<= 1) {
        int t = __shfl_up(v, off, 64);
        if (lane >= off) v += t;
    }
    boff[lane] = v - orig;
}

__global__ __launch_bounds__(256) void scan3_kernel(int* __restrict__ row_ptr,
                                                    const int* __restrict__ boff) {
    int add = boff[blockIdx.x];
    int base = blockIdx.x * 1024 + threadIdx.x * 4;
#pragma unroll
    for (int j = 0; j < 4; ++j) {
        int i = base + j;
        if (i <= NV) row_ptr[i] += add;
    }
}

__global__ __launch_bounds__(256) void bscatter_kernel(
        const uint32* __restrict__ bukx, const uint32* __restrict__ buky,
        const int* __restrict__ gcur, const int* __restrict__ row_ptr,
        int* __restrict__ csr_src, uint32* __restrict__ csr_ea) {
    __shared__ int cur[256];
    const int b = blockIdx.x, t = threadIdx.x;
    cur[t] = row_ptr[b * 256 + t];
    __syncthreads();
    const int base = b * BCAP;
    int cnt = gcur[b] - base;
    if (cnt > BCAP) cnt = BCAP;
    for (int i = t; i < cnt; i += 256) {
        uint32 x = bukx[base + i];
        uint32 y = buky[base + i];
        int p = atomicAdd(&cur[(x >> 16) & 255], 1);
        csr_src[p] = (int)(x & 0xFFFFu);
        csr_ea[p] = y;
    }
}

// ---------------------------------------------------------------------------
// MFMA GEMM, full 128 cols per block: HW = H @ W + fused attention dots.
__global__ __launch_bounds__(256) void gemm_kernel(
        const uint32* __restrict__ Hu, const u16b* __restrict__ WBl,
        const float* __restrict__ PARl, uint32* __restrict__ HWu,
        float* __restrict__ ssrc, float* __restrict__ sdst) {
    __shared__ float hs[64 * 129];
    __shared__ float pp[512];
    const int tid = threadIdx.x;
    const int lane = tid & 63;
    const int wave = tid >> 6;
    const int quad = lane >> 4;
    const int n0 = blockIdx.x * 64;
    const int m = n0 + wave * 16 + (lane & 15);

    const u16b* hrow = (const u16b*)Hu + (size_t)m * 128;
    short8 a0 = *(const short8*)(hrow + 0  + quad * 8);
    short8 a1 = *(const short8*)(hrow + 32 + quad * 8);
    short8 a2 = *(const short8*)(hrow + 64 + quad * 8);
    short8 a3 = *(const short8*)(hrow + 96 + quad * 8);

#pragma unroll
    for (int nt = 0; nt < 8; ++nt) {
        const u16b* bbase = WBl + ((size_t)nt * 512 + lane * 8);
        short8 b0 = *(const short8*)(bbase + 0 * 4096);
        short8 b1 = *(const short8*)(bbase + 1 * 4096);
        short8 b2 = *(const short8*)(bbase + 2 * 4096);
        short8 b3 = *(const short8*)(bbase + 3 * 4096);
        float4v acc = {0.f, 0.f, 0.f, 0.f};
        acc = __builtin_amdgcn_mfma_f32_16x16x32_bf16(a0, b0, acc, 0, 0, 0);
        acc = __builtin_amdgcn_mfma_f32_16x16x32_bf16(a1, b1, acc, 0, 0, 0);
        acc = __builtin_amdgcn_mfma_f32_16x16x32_bf16(a2, b2, acc, 0, 0, 0);
        acc = __builtin_amdgcn_mfma_f32_16x16x32_bf16(a3, b3, acc, 0, 0, 0);
#pragma unroll
        for (int r = 0; r < 4; ++r)
            hs[(wave * 16 + quad * 4 + r) * 129 + nt * 16 + (lane & 15)] = acc[r];
    }
    __syncthreads();

    {
        const int mn = tid & 63, cg = tid >> 6;
        const float* Asr = PARl + P_ASRC;
        const float* Ads = PARl + P_ADST;
        const float* row = hs + mn * 129 + cg * 32;
        float ps = 0.f, pd = 0.f;
#pragma unroll
        for (int j = 0; j < 32; ++j) {
            float v = row[j];
            ps = fmaf(v, Asr[cg * 32 + j], ps);
            pd = fmaf(v, Ads[cg * 32 + j], pd);
        }
        pp[tid] = ps; pp[256 + tid] = pd;
    }
    __syncthreads();
    if (tid < 64) {
        ssrc[n0 + tid] = pp[tid] + pp[64 + tid] + pp[128 + tid] + pp[192 + tid];
        sdst[n0 + tid] = pp[256 + tid] + pp[320 + tid] + pp[384 + tid] + pp[448 + tid];
    }

#pragma unroll
    for (int i = 0; i < 4; ++i) {
        int flat = i * 2048 + tid * 8;
        int n = flat >> 7, c = flat & 127;
        const float* p = hs + n * 129 + c;
        uint4 v;
        v.x = pack2(p[0], p[1]); v.y = pack2(p[2], p[3]);
        v.z = pack2(p[4], p[5]); v.w = pack2(p[6], p[7]);
        *(uint4*)(HWu + (size_t)(n0 + n) * 64 + c / 2) = v;
    }
}

// ---------------------------------------------------------------------------
// Hidden-layer attention + aggregation, one wave per dst node.
// Lane-parallel softmax precompute (edge j in lane j, deg<=64 fast path),
// factored edge-feature term, readlane-broadcast gather loop.
// Layer 3 additionally emits hw5[n] = dot(h_out[n], W5).
__global__ __launch_bounds__(256) void agg_kernel(
        const uint32* __restrict__ HWu, const float* __restrict__ ssrc,
        const float* __restrict__ sdst, const int* __restrict__ csr_src,
        const uint32* __restrict__ csr_ea, const int* __restrict__ row_ptr,
        const float* __restrict__ PAR, int layer, uint32* __restrict__ HoutU,
        float* __restrict__ hw5out, int wantw5) {
    const int lane = threadIdx.x & 63;
    const int n = blockIdx.x * 4 + (threadIdx.x >> 6);
    const int begin = __builtin_amdgcn_readfirstlane(row_ptr[n]);
    const int deg   = __builtin_amdgcn_readfirstlane(row_ptr[n + 1]) - begin;
    const float c0 = PAR[P_CVEC + 2 * layer], c1 = PAR[P_CVEC + 2 * layer + 1];
    const float sd = sdst[n];

    // phase 1: edge lane's logit (first 64 edges in-register)
    int   sv = 0;
    uint32 eb = 0;
    float L = -3.4e38f;
    if (lane < deg) {
        sv = csr_src[begin + lane];
        eb = csr_ea[begin + lane];
        L = fmaf(hi2f(eb), c1, fmaf(lo2f(eb), c0, ssrc[sv] + sd));
        L = (L > 0.f) ? L : 0.2f * L;
    }
    float m = L;
    for (int j0 = 64; j0 < deg; j0 += 64) {        // rare (deg > 64)
        int j = j0 + lane;
        if (j < deg) {
            int s2 = csr_src[begin + j];
            uint32 e2 = csr_ea[begin + j];
            float L2 = fmaf(hi2f(e2), c1, fmaf(lo2f(e2), c0, ssrc[s2] + sd));
            L2 = (L2 > 0.f) ? L2 : 0.2f * L2;
            m = fmaxf(m, L2);
        }
    }
#pragma unroll
    for (int o = 32; o; o >>= 1) m = fmaxf(m, __shfl_xor(m, o, 64));

    float ex = (lane < deg) ? __expf(L - m) : 0.f;
    float dsum = ex, sx = ex * lo2f(eb), sy = ex * hi2f(eb);
    for (int j0 = 64; j0 < deg; j0 += 64) {        // rare
        int j = j0 + lane;
        if (j < deg) {
            int s2 = csr_src[begin + j];
            uint32 e2 = csr_ea[begin + j];
            float L2 = fmaf(hi2f(e2), c1, fmaf(lo2f(e2), c0, ssrc[s2] + sd));
            L2 = (L2 > 0.f) ? L2 : 0.2f * L2;
            float x2 = __expf(L2 - m);
            dsum += x2; sx = fmaf(x2, lo2f(e2), sx); sy = fmaf(x2, hi2f(e2), sy);
        }
    }
#pragma unroll
    for (int o = 32; o; o >>= 1) {
        dsum += __shfl_xor(dsum, o, 64);
        sx   += __shfl_xor(sx, o, 64);
        sy   += __shfl_xor(sy, o, 64);
    }

    // phase 2: weighted row gather. acc = sum ex*hw[src]  (per-lane 2 channels)
    const int dmain = (deg < 64) ? deg : 64;
    const uint32 exu = __float_as_uint(ex);
    float acc0 = 0.f, acc1 = 0.f;
    int jj = 0;
    for (; jj + 8 <= dmain; jj += 8) {
        int s8[8]; float e8[8]; uint32 hv[8];
#pragma unroll
        for (int q = 0; q < 8; ++q) {
            s8[q] = __builtin_amdgcn_readlane(sv, jj + q);
            e8[q] = __uint_as_float(__builtin_amdgcn_readlane((int)exu, jj + q));
        }
#pragma unroll
        for (int q = 0; q < 8; ++q) hv[q] = HWu[(size_t)s8[q] * 64 + lane];
#pragma unroll
        for (int q = 0; q < 8; ++q) {
            acc0 = fmaf(e8[q], lo2f(hv[q]), acc0);
            acc1 = fmaf(e8[q], hi2f(hv[q]), acc1);
        }
    }
    for (; jj < dmain; ++jj) {
        int s = __builtin_amdgcn_readlane(sv, jj);
        float e1v = __uint_as_float(__builtin_amdgcn_readlane((int)exu, jj));
        uint32 hb = HWu[(size_t)s * 64 + lane];
        acc0 = fmaf(e1v, lo2f(hb), acc0);
        acc1 = fmaf(e1v, hi2f(hb), acc1);
    }
    for (jj = 64; jj < deg; ++jj) {                // rare tail
        int s = csr_src[begin + jj];
        uint32 e2 = csr_ea[begin + jj];
        float L2 = fmaf(hi2f(e2), c1, fmaf(lo2f(e2), c0, ssrc[s] + sd));
        L2 = (L2 > 0.f) ? L2 : 0.2f * L2;
        float x2 = __expf(L2 - m);
        uint32 hb = HWu[(size_t)s * 64 + lane];
        acc0 = fmaf(x2, lo2f(hb), acc0);
        acc1 = fmaf(x2, hi2f(hb), acc1);
    }

    const int ch = lane * 2;
    const float* WEl = PAR + P_WE + layer * 256;
    const float inv = 1.f / (dsum + 1e-16f);
    const float* Bl = PAR + P_BIAS + layer * DD;
    float t0 = fmaf(sy, WEl[DD + ch],     fmaf(sx, WEl[ch],     acc0));
    float t1 = fmaf(sy, WEl[DD + ch + 1], fmaf(sx, WEl[ch + 1], acc1));
    float o0 = fmaf(t0, inv, Bl[ch]);
    float o1 = fmaf(t1, inv, Bl[ch + 1]);
    o0 = (o0 > 0.f) ? o0 : 0.01f * o0;
    o1 = (o1 > 0.f) ? o1 : 0.01f * o1;
    HoutU[(size_t)n * 64 + lane] = pack2(o0, o1);

    if (wantw5) {
        float p = o0 * PAR[P_W5 + ch] + o1 * PAR[P_W5 + ch + 1];
#pragma unroll
        for (int o = 32; o; o >>= 1) p += __shfl_xor(p, o, 64);
        if (lane == 0) hw5out[n] = p;
    }
}

// ---------------------------------------------------------------------------
__global__ __launch_bounds__(256) void final_kernel(
        const float* __restrict__ hw5, const int* __restrict__ csr_src,
        const uint32* __restrict__ csr_ea, const int* __restrict__ row_ptr,
        const float* __restrict__ PAR, const int* __restrict__ FLAG,
        void* __restrict__ out) {
    const int flag = FLAG[0];
    int lane = threadIdx.x & 63;
    int n = blockIdx.x * 4 + (threadIdx.x >> 6);
    int begin = __builtin_amdgcn_readfirstlane(row_ptr[n]);
    int deg   = __builtin_amdgcn_readfirstlane(row_ptr[n + 1]) - begin;
    float c50 = PAR[P_CVEC + 8], c51 = PAR[P_CVEC + 9];
    float ce0 = PAR[P_CVEC + 10], ce1 = PAR[P_CVEC + 11];
    float b5v = PAR[P_SC5], a5s = PAR[P_SC5 + 1];
    float hd = PAR[P_SC5 + 2] * hw5[n];

    float m = -3.4e38f;
    for (int j0 = 0; j0 < deg; j0 += 64) {
        int j = j0 + lane;
        if (j < deg) {
            int s = csr_src[begin + j];
            uint32 eb = csr_ea[begin + j];
            float L = fmaf(hi2f(eb), c51, fmaf(lo2f(eb), c50, fmaf(a5s, hw5[s], hd)));
            L = (L > 0.f) ? L : 0.2f * L;
            m = fmaxf(m, L);
        }
    }
#pragma unroll
    for (int o = 32; o; o >>= 1) m = fmaxf(m, __shfl_xor(m, o, 64));

    float dsum = 0.f, msum = 0.f;
    for (int j0 = 0; j0 < deg; j0 += 64) {
        int j = j0 + lane;
        if (j < deg) {
            int s = csr_src[begin + j];
            uint32 eb = csr_ea[begin + j];
            float hs5 = hw5[s];
            float L = fmaf(hi2f(eb), c51, fmaf(lo2f(eb), c50, fmaf(a5s, hs5, hd)));
            L = (L > 0.f) ? L : 0.2f * L;
            float ex = __expf(L - m);
            dsum += ex;
            msum = fmaf(ex, hs5 + fmaf(hi2f(eb), ce1, lo2f(eb) * ce0), msum);
        }
    }
#pragma unroll
    for (int o = 32; o; o >>= 1) {
        dsum += __shfl_xor(dsum, o, 64);
        msum += __shfl_xor(msum, o, 64);
    }
    if (lane == 0) {
        float r = msum / (dsum + 1e-16f) + b5v;
        if (flag) ((float*)out)[n] = r;
        else      ((u16b*)out)[n] = (u16b)f2bf_bits(r);
    }
}

// ---------------------------------------------------------------------------
extern "C" void kernel_launch(void* const* d_in, const int* in_sizes, int n_in,
                              void* d_out, int out_size, void* d_ws, size_t ws_size,
                              hipStream_t stream) {
    const void* x   = d_in[0];
    const int*  ei  = (const int*)d_in[1];
    const void* ea  = d_in[2];
    const int*  cur = (const int*)d_in[3];
    const void* vge = d_in[4];
    const void* vnd = d_in[5];
    const void* pW  = d_in[6];
    const void* pb  = d_in[7];
    const void* Ws  = d_in[8];
    const void* bs  = d_in[9];
    const void* asr = d_in[10];
    const void* ads = d_in[11];
    const void* aeg = d_in[12];
    const void* Wes = d_in[13];
    const void* W5  = d_in[14];
    const void* b5  = d_in[15];
    const void* as5 = d_in[16];
    const void* ad5 = d_in[17];
    const void* ae5 = d_in[18];
    const void* We5 = d_in[19];
    (void)in_sizes; (void)n_in; (void)out_size;

    const int* e_src = ei;
    const int* e_dst = ei + EE;

    size_t off = 0;
    char* base = (char*)d_ws;
    auto carve = [&](size_t bytes) {
        void* p = base + off;
        off += (bytes + 255) & ~(size_t)255;
        return p;
    };
    int*    FLAG   = (int*)carve(256);
    float*  PAR    = (float*)carve((size_t)P_TOT * 4);
    u16b*   WB     = (u16b*)carve(4 * DD * DD * 2);      // MFMA B fragments
    uint32* H0     = (uint32*)carve((size_t)NV * DD * 2);
    uint32* H1     = (uint32*)carve((size_t)NV * DD * 2); // also bucket storage
    float*  SS     = (float*)carve(NV * 4);
    float*  SD     = (float*)carve(NV * 4);
    float*  HW5v   = (float*)carve(NV * 4);
    int*    COUNTS = (int*)carve(65536 * 4);
    int*    ROWPTR = (int*)carve(65536 * 4);
    int*    GCUR   = (int*)carve(256 * 4);
    int*    PART   = (int*)carve(256 * 4);
    int*    BOFF   = (int*)carve(256 * 4);
    int*    CSRS   = (int*)carve((size_t)EE * 4);
    uint32* CSREA  = (uint32*)carve((size_t)EE * 4);
    size_t need = off;

    // bucket storage aliases H1 (used strictly before the layer loop)
    uint32* BUKX = H1;
    uint32* BUKY = H1 + (size_t)NBUK * BCAP;

    sniff_kernel<<<1, 256, 0, stream>>>((const unsigned short*)ea, FLAG);

    if (need > ws_size) {
        zero_out_kernel<<<(NV + 255) / 256, 256, 0, stream>>>(
            d_out, FLAG, (float)(ws_size >> 20));
        return;
    }

    prep_kernel<<<5, 256, 0, stream>>>(Wes, aeg, We5, ae5, asr, ads, bs,
                                       W5, b5, as5, ad5, FLAG, PAR);
    prepack_kernel<<<32, 256, 0, stream>>>(Ws, FLAG, WB);
    proj_kernel<<<NV / 4, 256, 0, stream>>>(x, pW, pb, cur, vge, vnd, FLAG, H0);

    init_kernel<<<2, 256, 0, stream>>>(GCUR, COUNTS);
    bucketize_kernel<<<EE / 4096, 256, 0, stream>>>(e_src, e_dst, ea, FLAG,
                                                    GCUR, BUKX, BUKY);
    bcount_kernel<<<NBUK, 256, 0, stream>>>(BUKX, GCUR, COUNTS);
    scan1_kernel<<<63, 256, 0, stream>>>(COUNTS, ROWPTR, PART);
    scan2_kernel<<<1, 64, 0, stream>>>(PART, BOFF, 63);
    scan3_kernel<<<63, 256, 0, stream>>>(ROWPTR, BOFF);
    bscatter_kernel<<<NBUK, 256, 0, stream>>>(BUKX, BUKY, GCUR, ROWPTR,
                                              CSRS, CSREA);

    for (int l = 0; l < 4; ++l) {
        gemm_kernel<<<NV / 64, 256, 0, stream>>>(
            H0, WB + (size_t)l * 16384, PAR + l * DD, H1, SS, SD);
        agg_kernel<<<NV / 4, 256, 0, stream>>>(
            H1, SS, SD, CSRS, CSREA, ROWPTR, PAR, l, H0, HW5v, (l == 3) ? 1 : 0);
    }

    final_kernel<<<NV / 4, 256, 0, stream>>>(HW5v, CSRS, CSREA, ROWPTR, PAR,
                                             FLAG, d_out);
}